// Round 2
// 9191.235 us; speedup vs baseline: 1.4617x; 1.4617x over previous
//
#include <hip/hip_runtime.h>
#include <hip/hip_bf16.h>
#include <cstddef>

#define D_   1024
#define DI_  2048
#define DS_  16
#define DTR_ 64
#define KC_  4
#define HR_  16
#define DHR_ 64
#define HA_  32
#define DHA_ 32
#define NM_  6
#define NR_  4
#define NT_  2
#define B_   2
#define L_   1024
#define NBL  (B_*L_)   // 2048 rows

typedef __hip_bfloat16 bf16;

__device__ __forceinline__ float bfbits2f(unsigned short u) {
    return __uint_as_float(((unsigned int)u) << 16);
}
__device__ __forceinline__ float b2f(bf16 x) { return __bfloat162float(x); }
// dtype-dispatched model-input load: bf==1 -> bf16, bf==0 -> fp32
__device__ __forceinline__ float ldf(const void* p, long i, int bf) {
    if (bf) return bfbits2f(((const unsigned short*)p)[i]);
    return ((const float*)p)[i];
}
__device__ __forceinline__ float softplus_f(float x) {
    return x > 20.f ? x : log1pf(__expf(x));
}
__device__ __forceinline__ float silu_f(float x) {
    return x / (1.f + __expf(-x));
}

// ---------------------------------------------------------------------------
// Diagnostic writer (fp32 out): zeros the output, writes a code into out[0].
// ---------------------------------------------------------------------------
__global__ __launch_bounds__(256) void diag_k(float* __restrict__ out, float code)
{
    const int idx = blockIdx.x * 256 + threadIdx.x;
    if (idx < NBL * 3) out[idx] = (idx == 0 ? code : 0.f);
}

// ---------------------------------------------------------------------------
// Input dtype detection (1 wave): fp32 data misread as bf16 has garbage
// exponents in the low half-words.
// ---------------------------------------------------------------------------
__global__ __launch_bounds__(64) void detect_k(const void* __restrict__ x,
                                               int* __restrict__ flag)
{
    const unsigned short* u = (const unsigned short*)x;
    int local = 0;
    for (int i = threadIdx.x; i < 1024; i += 64) {
        const float av = fabsf(bfbits2f(u[i]));
        if (!(av < 1e6f)) local = 1;   // catches huge and NaN
    }
    const unsigned long long b = __ballot(local);
    if (threadIdx.x == 0) flag[0] = b ? 0 : 1;  // 1 => inputs are bf16
}

// ---------------------------------------------------------------------------
// Generic GEMM: C[M,N] = act(A[M,K] @ W[K,N] + bias) (+ C if acc, fp32 C only)
// A: fp32 or bf16 (aDt). W/bias: model dtype (runtime flag). C: fp32 or bf16.
// ---------------------------------------------------------------------------
#define BM 64
#define BN 64
#define BK 16

__global__ __launch_bounds__(256) void gemm_k(
    const void* __restrict__ A, int lda, int aDt,
    const void* __restrict__ W, long woff,
    const void* __restrict__ bias, long boff, int hasBias,
    void* __restrict__ C, int ldc, int cDt,
    int N, int K, int act, int acc,
    const int* __restrict__ flagp)
{
    const int bf = *flagp;
    __shared__ float As[BK][BM];
    __shared__ float Ws[BK][BN];
    const int bm = blockIdx.y * BM;
    const int bn = blockIdx.x * BN;
    const int tid = threadIdx.x;
    const int ty = tid >> 4;
    const int tx = tid & 15;

    float accv[4][4];
    #pragma unroll
    for (int i = 0; i < 4; ++i)
        #pragma unroll
        for (int j = 0; j < 4; ++j) accv[i][j] = 0.f;

    for (int k0 = 0; k0 < K; k0 += BK) {
        {   // A tile: row r, 4 consecutive k
            const int r  = tid >> 2;
            const int c4 = (tid & 3) << 2;
            const size_t aoff = (size_t)(bm + r) * lda + k0 + c4;
            float a0, a1, a2, a3;
            if (aDt) {
                const ushort4 v = *(const ushort4*)((const unsigned short*)A + aoff);
                a0 = bfbits2f(v.x); a1 = bfbits2f(v.y);
                a2 = bfbits2f(v.z); a3 = bfbits2f(v.w);
            } else {
                const float4 v = *(const float4*)((const float*)A + aoff);
                a0 = v.x; a1 = v.y; a2 = v.z; a3 = v.w;
            }
            As[c4 + 0][r] = a0; As[c4 + 1][r] = a1;
            As[c4 + 2][r] = a2; As[c4 + 3][r] = a3;
        }
        {   // W tile: k row r, 4 consecutive n
            const int r = tid >> 4;
            const int c = (tid & 15) << 2;
            const int gn = bn + c;
            float w0 = 0.f, w1 = 0.f, w2 = 0.f, w3 = 0.f;
            const long wbase = woff + (long)(k0 + r) * N + gn;
            if (gn + 3 < N) {
                if (bf) {
                    const ushort4 wv = *(const ushort4*)((const unsigned short*)W + wbase);
                    w0 = bfbits2f(wv.x); w1 = bfbits2f(wv.y);
                    w2 = bfbits2f(wv.z); w3 = bfbits2f(wv.w);
                } else {
                    const float4 wv = *(const float4*)((const float*)W + wbase);
                    w0 = wv.x; w1 = wv.y; w2 = wv.z; w3 = wv.w;
                }
            } else {
                if (gn + 0 < N) w0 = ldf(W, wbase + 0, bf);
                if (gn + 1 < N) w1 = ldf(W, wbase + 1, bf);
                if (gn + 2 < N) w2 = ldf(W, wbase + 2, bf);
                if (gn + 3 < N) w3 = ldf(W, wbase + 3, bf);
            }
            Ws[r][c + 0] = w0; Ws[r][c + 1] = w1;
            Ws[r][c + 2] = w2; Ws[r][c + 3] = w3;
        }
        __syncthreads();
        #pragma unroll
        for (int kk = 0; kk < BK; ++kk) {
            float a_[4], b_[4];
            #pragma unroll
            for (int i = 0; i < 4; ++i) a_[i] = As[kk][ty * 4 + i];
            #pragma unroll
            for (int j = 0; j < 4; ++j) b_[j] = Ws[kk][tx * 4 + j];
            #pragma unroll
            for (int i = 0; i < 4; ++i)
                #pragma unroll
                for (int j = 0; j < 4; ++j)
                    accv[i][j] = fmaf(a_[i], b_[j], accv[i][j]);
        }
        __syncthreads();
    }

    #pragma unroll
    for (int i = 0; i < 4; ++i) {
        const int row = bm + ty * 4 + i;
        #pragma unroll
        for (int j = 0; j < 4; ++j) {
            const int col = bn + tx * 4 + j;
            if (col < N) {
                float r = accv[i][j];
                if (hasBias) r += ldf(bias, boff + col, bf);
                if (act == 1) r = softplus_f(r);
                if (cDt) {
                    ((bf16*)C)[(size_t)row * ldc + col] = __float2bfloat16(r);
                } else {
                    float* cp = (float*)C + (size_t)row * ldc + col;
                    if (acc) r += *cp;
                    *cp = r;
                }
            }
        }
    }
}

// ---------------------------------------------------------------------------
__global__ __launch_bounds__(256) void cast3_k(const void* __restrict__ x,
    float* __restrict__ a, float* __restrict__ b, float* __restrict__ c,
    const int* __restrict__ flagp)
{
    const int bf = *flagp;
    const int idx = blockIdx.x * 256 + threadIdx.x;
    const float v = ldf(x, idx, bf);
    a[idx] = v; b[idx] = v; c[idx] = v;
}

// ---------------------------------------------------------------------------
__global__ __launch_bounds__(256) void rmsnorm_k(const float* __restrict__ x,
    const void* __restrict__ wgt, long woff, float* __restrict__ out,
    const int* __restrict__ flagp)
{
    const int bf = *flagp;
    const int row = blockIdx.x;
    const float* xr = x + (size_t)row * D_;
    float ss = 0.f;
    for (int i = threadIdx.x; i < D_; i += 256) { const float v = xr[i]; ss = fmaf(v, v, ss); }
    #pragma unroll
    for (int msk = 1; msk < 64; msk <<= 1) ss += __shfl_xor(ss, msk);
    __shared__ float red[4];
    if ((threadIdx.x & 63) == 0) red[threadIdx.x >> 6] = ss;
    __syncthreads();
    ss = red[0] + red[1] + red[2] + red[3];
    const float scale = rsqrtf(ss * (1.f / D_) + 1e-6f);
    float* orow = out + (size_t)row * D_;
    for (int i = threadIdx.x; i < D_; i += 256)
        orow[i] = xr[i] * scale * ldf(wgt, woff + i, bf);
}

// ---------------------------------------------------------------------------
// Depthwise causal conv (K=4) + SiLU. xc = cols [0,DI) of xz16 (stride 2*DI).
// ---------------------------------------------------------------------------
__global__ __launch_bounds__(256) void conv_silu_k(const bf16* __restrict__ xz,
    const void* __restrict__ cw, long cwoff, const void* __restrict__ cb, long cboff,
    bf16* __restrict__ out, const int* __restrict__ flagp)
{
    const int bf = *flagp;
    const int idx = blockIdx.x * 256 + threadIdx.x;
    const int c = idx & (DI_ - 1);
    const int l = (idx >> 11) & (L_ - 1);
    const int b = idx >> 21;
    float acc = ldf(cb, cboff + c, bf);
    #pragma unroll
    for (int j = 0; j < KC_; ++j) {
        const int ls = l - (KC_ - 1) + j;
        if (ls >= 0)
            acc = fmaf(b2f(xz[((size_t)(b * L_ + ls)) * (2 * DI_) + c]),
                       ldf(cw, cwoff + j * DI_ + c, bf), acc);
    }
    out[idx] = __float2bfloat16(silu_f(acc));
}

// ---------------------------------------------------------------------------
// Mamba selective scan — chunk-parallel (linear recurrence is associative).
// Block = one (b,d): 16 s-lanes x 16 chunks of 64 steps.
// Pass 1: per-chunk (P = prod dA, S = h_end | h0=0).  LDS combine gives each
// chunk its true h0.  Pass 2: rescan chunk (L2-warm) producing y.
// Serial depth 1024 -> 128; occupancy 4 -> 32 waves/CU.
// ---------------------------------------------------------------------------
#define MS_NCH 16
#define MS_CH  (L_ / MS_NCH)   // 64

__global__ __launch_bounds__(256) void mamba_scan_k(
    const bf16* __restrict__ u, const bf16* __restrict__ dlt,
    const float* __restrict__ xdbl, bf16* __restrict__ xz,
    const void* __restrict__ Alog, long aoff, const void* __restrict__ Dp, long doff,
    const int* __restrict__ flagp)
{
    const int bf = *flagp;
    const int bid = blockIdx.x;            // B*DI = 4096
    const int d = bid & (DI_ - 1);
    const int b = bid >> 11;
    const int s = threadIdx.x & (DS_ - 1);
    const int c = threadIdx.x >> 4;        // chunk 0..15
    const float Av = -__expf(ldf(Alog, aoff + d * DS_ + s, bf));
    const float Dv = ldf(Dp, doff + d, bf);

    __shared__ float Pl[MS_NCH][DS_];
    __shared__ float Sl[MS_NCH][DS_];

    const int l0 = c * MS_CH;

    // pass 1: chunk-local (P, S)
    float P = 1.f, S = 0.f;
    for (int i = 0; i < MS_CH; ++i) {
        const size_t row = (size_t)(b * L_ + l0 + i);
        const float ut = b2f(u[row * DI_ + d]);
        const float dt = b2f(dlt[row * DI_ + d]);
        const float Bv = xdbl[row * 96 + 64 + s];
        const float dA = __expf(dt * Av);
        P *= dA;
        S = fmaf(S, dA, dt * ut * Bv);
    }
    Pl[c][s] = P; Sl[c][s] = S;
    __syncthreads();

    // prefix combine: h at this chunk's start
    float hs = 0.f;
    for (int cc = 0; cc < c; ++cc) hs = fmaf(hs, Pl[cc][s], Sl[cc][s]);

    // pass 2: rescan with true h0, reduce over s, write y
    for (int i = 0; i < MS_CH; ++i) {
        const size_t row = (size_t)(b * L_ + l0 + i);
        const float ut = b2f(u[row * DI_ + d]);
        const float dt = b2f(dlt[row * DI_ + d]);
        const float Bv = xdbl[row * 96 + 64 + s];
        const float Cv = xdbl[row * 96 + 80 + s];
        const float dA = __expf(dt * Av);
        hs = fmaf(hs, dA, dt * ut * Bv);
        float yp = hs * Cv;
        yp += __shfl_xor(yp, 1, 16);
        yp += __shfl_xor(yp, 2, 16);
        yp += __shfl_xor(yp, 4, 16);
        yp += __shfl_xor(yp, 8, 16);
        if (s == 0) {
            const float z = b2f(xz[row * (2 * DI_) + DI_ + d]);
            xz[row * (2 * DI_) + d] = __float2bfloat16((yp + Dv * ut) * silu_f(z));
        }
    }
}

// ---------------------------------------------------------------------------
__global__ __launch_bounds__(256) void rwkv_mix_k(const float* __restrict__ xn,
    const void* __restrict__ mu, long muoff, bf16* __restrict__ o0,
    bf16* __restrict__ o1, bf16* __restrict__ o2, const int* __restrict__ flagp)
{
    const int bf = *flagp;
    const int idx = blockIdx.x * 256 + threadIdx.x;
    const int d = idx & (D_ - 1);
    const int l = (idx >> 10) & (L_ - 1);
    const float cur = xn[idx];
    const float prev = (l > 0) ? xn[idx - D_] : 0.f;
    const float m0 = ldf(mu, muoff + d, bf);
    const float m1 = ldf(mu, muoff + D_ + d, bf);
    const float m2 = ldf(mu, muoff + 2 * D_ + d, bf);
    o0[idx] = __float2bfloat16(cur * m0 + prev * (1.f - m0));
    o1[idx] = __float2bfloat16(cur * m1 + prev * (1.f - m1));
    o2[idx] = __float2bfloat16(cur * m2 + prev * (1.f - m2));
}

// ---------------------------------------------------------------------------
// RWKV scan — chunk-parallel.  S_{l+1} = w*S_l + k*v with constant w, so the
// chunk carry factor is w^CH = exp(-CH*exp(wlog)) in closed form.
// Block = one (b,h,v): 64 k-lanes x 16 chunks of 64 steps (1024 threads).
// ---------------------------------------------------------------------------
#define RW_NCH 16
#define RW_CH  (L_ / RW_NCH)   // 64

__global__ __launch_bounds__(1024) void rwkv_scan_k(const bf16* __restrict__ R,
    const bf16* __restrict__ Kb, const bf16* __restrict__ V,
    const void* __restrict__ wlog, long woff, const void* __restrict__ uu, long uoff,
    bf16* __restrict__ Y, const int* __restrict__ flagp)
{
    const int bf = *flagp;
    const int bid = blockIdx.x;           // B*HR*DHR = 2048
    const int v = bid & (DHR_ - 1);
    const int h = (bid >> 6) & (HR_ - 1);
    const int b = bid >> 10;
    const int k = threadIdx.x & 63;
    const int c = threadIdx.x >> 6;       // chunk 0..15
    const float ew = __expf(ldf(wlog, woff + h * DHR_ + k, bf));
    const float w  = __expf(-ew);
    const float wC = __expf(-ew * (float)RW_CH);   // w^CH
    const float uv = ldf(uu, uoff + h * DHR_ + k, bf);

    __shared__ float Se[RW_NCH][64];

    const int l0 = c * RW_CH;

    // pass 1: chunk-local S_end (S0 = 0)
    float S = 0.f;
    for (int i = 0; i < RW_CH; ++i) {
        const size_t off = ((size_t)(b * L_ + l0 + i)) * D_ + h * DHR_;
        const float kk = b2f(Kb[off + k]);
        const float vt = b2f(V[off + v]);
        S = fmaf(w, S, kk * vt);
    }
    Se[c][k] = S;
    __syncthreads();

    // prefix: S at this chunk's start
    S = 0.f;
    for (int cc = 0; cc < c; ++cc) S = fmaf(wC, S, Se[cc][k]);

    // pass 2: rescan with true S0, reduce over k, write y
    for (int i = 0; i < RW_CH; ++i) {
        const size_t off = ((size_t)(b * L_ + l0 + i)) * D_ + h * DHR_;
        const float r  = b2f(R[off + k]);
        const float kk = b2f(Kb[off + k]);
        const float vt = b2f(V[off + v]);
        const float kv = kk * vt;
        float yp = r * fmaf(uv, kv, S);
        S = fmaf(w, S, kv);
        yp += __shfl_xor(yp, 1);
        yp += __shfl_xor(yp, 2);
        yp += __shfl_xor(yp, 4);
        yp += __shfl_xor(yp, 8);
        yp += __shfl_xor(yp, 16);
        yp += __shfl_xor(yp, 32);
        if (k == 0) Y[off + v] = __float2bfloat16(yp);
    }
}

// ---------------------------------------------------------------------------
// MHA flash attention, thread per query row, bf16 Q/K/V/O.
// ---------------------------------------------------------------------------
__global__ __launch_bounds__(256) void mha_attn_k(const bf16* __restrict__ Q,
    const bf16* __restrict__ Kx, const bf16* __restrict__ V, bf16* __restrict__ O)
{
    const int b = blockIdx.z, h = blockIdx.y;
    const int ql = blockIdx.x * 256 + threadIdx.x;
    __shared__ float Ks[32][33];
    __shared__ float Vs[32][33];
    float q[32], o[32];
    #pragma unroll
    for (int d = 0; d < 32; ++d) o[d] = 0.f;
    float mrun = -1e30f, lsum = 0.f;
    const size_t qoff = ((size_t)(b * L_ + ql)) * D_ + h * DHA_;
    #pragma unroll
    for (int d = 0; d < 32; ++d) q[d] = b2f(Q[qoff + d]) * 0.1767766952966369f;

    for (int kt = 0; kt < L_; kt += 32) {
        __syncthreads();
        {
            const int r = threadIdx.x >> 3;
            const int c = (threadIdx.x & 7) << 2;
            const size_t koff = ((size_t)(b * L_ + kt + r)) * D_ + h * DHA_ + c;
            const ushort4 k4 = *(const ushort4*)((const unsigned short*)Kx + koff);
            Ks[r][c + 0] = bfbits2f(k4.x); Ks[r][c + 1] = bfbits2f(k4.y);
            Ks[r][c + 2] = bfbits2f(k4.z); Ks[r][c + 3] = bfbits2f(k4.w);
            const ushort4 v4 = *(const ushort4*)((const unsigned short*)V + koff);
            Vs[r][c + 0] = bfbits2f(v4.x); Vs[r][c + 1] = bfbits2f(v4.y);
            Vs[r][c + 2] = bfbits2f(v4.z); Vs[r][c + 3] = bfbits2f(v4.w);
        }
        __syncthreads();
        for (int j = 0; j < 32; ++j) {
            float s = 0.f;
            #pragma unroll
            for (int d = 0; d < 32; ++d) s = fmaf(q[d], Ks[j][d], s);
            const float mn = fmaxf(mrun, s);
            const float corr = __expf(mrun - mn);
            const float p = __expf(s - mn);
            lsum = lsum * corr + p;
            #pragma unroll
            for (int d = 0; d < 32; ++d) o[d] = o[d] * corr + p * Vs[j][d];
            mrun = mn;
        }
    }
    const float inv = 1.f / lsum;
    #pragma unroll
    for (int d = 0; d < 32; ++d) O[qoff + d] = __float2bfloat16(o[d] * inv);
}

// ---------------------------------------------------------------------------
// Final: logits = [m,r,t] @ f_W + f_b; softmax over 3; fp32 out.
// ---------------------------------------------------------------------------
__global__ __launch_bounds__(256) void final_k(const float* __restrict__ m,
    const float* __restrict__ r, const float* __restrict__ t,
    const void* __restrict__ fW, const void* __restrict__ fb,
    float* __restrict__ out, const int* __restrict__ flagp)
{
    const int bf = *flagp;
    const int row = blockIdx.x;
    float p0 = 0.f, p1 = 0.f, p2 = 0.f;
    for (int i = threadIdx.x; i < 3 * D_; i += 256) {
        float v;
        if (i < D_)          v = m[(size_t)row * D_ + i];
        else if (i < 2 * D_) v = r[(size_t)row * D_ + i - D_];
        else                 v = t[(size_t)row * D_ + i - 2 * D_];
        p0 = fmaf(v, ldf(fW, (long)i * 3 + 0, bf), p0);
        p1 = fmaf(v, ldf(fW, (long)i * 3 + 1, bf), p1);
        p2 = fmaf(v, ldf(fW, (long)i * 3 + 2, bf), p2);
    }
    #pragma unroll
    for (int msk = 1; msk < 64; msk <<= 1) {
        p0 += __shfl_xor(p0, msk);
        p1 += __shfl_xor(p1, msk);
        p2 += __shfl_xor(p2, msk);
    }
    __shared__ float red[4][3];
    if ((threadIdx.x & 63) == 0) {
        const int w = threadIdx.x >> 6;
        red[w][0] = p0; red[w][1] = p1; red[w][2] = p2;
    }
    __syncthreads();
    if (threadIdx.x == 0) {
        const float l0 = red[0][0] + red[1][0] + red[2][0] + red[3][0] + ldf(fb, 0, bf);
        const float l1 = red[0][1] + red[1][1] + red[2][1] + red[3][1] + ldf(fb, 1, bf);
        const float l2 = red[0][2] + red[1][2] + red[2][2] + red[3][2] + ldf(fb, 2, bf);
        const float mx = fmaxf(l0, fmaxf(l1, l2));
        const float e0 = __expf(l0 - mx), e1 = __expf(l1 - mx), e2 = __expf(l2 - mx);
        const float inv = 1.f / (e0 + e1 + e2);
        out[row * 3 + 0] = e0 * inv;
        out[row * 3 + 1] = e1 * inv;
        out[row * 3 + 2] = e2 * inv;
    }
}

// ---------------------------------------------------------------------------
extern "C" void kernel_launch(void* const* d_in, const int* in_sizes, int n_in,
                              void* d_out, int out_size, void* d_ws, size_t ws_size,
                              hipStream_t stream)
{
    float* out = (float*)d_out;

    // ---- self-diagnosis: verify input sizes (dict order) -------------------
    static const int expected[29] = {
        2097152, 6144, 25165824, 49152, 12288, 1179648, 786432, 12288,
        196608, 12288, 12582912, 4096, 12288, 4194304, 4194304, 4194304,
        4194304, 4096, 4096, 2097152, 2048, 2097152, 2048, 2097152, 2048,
        2097152, 2048, 9216, 3 };
    int bad = (n_in == 29) ? -1 : 29;
    if (bad < 0)
        for (int i = 0; i < 29; ++i)
            if (in_sizes[i] != expected[i]) { bad = i; break; }
    if (bad >= 0) {
        diag_k<<<24, 256, 0, stream>>>(out, 1000.f + 8.f * bad);
        return;
    }

    // ---- workspace layout (56.8 MB total) ----------------------------------
    const size_t REQ = 64 + 3ull * 8388608 + 8388608 + 16777216 + 8388608 + 786432;
    if (ws_size < REQ) {
        diag_k<<<24, 256, 0, stream>>>(out, 2048.f + (float)(ws_size >> 20));
        return;
    }
    char* base = (char*)d_ws;
    int*   flag = (int*)base;
    float* resM = (float*)(base + 64);
    float* resR = resM + 2097152;
    float* resT = resR + 2097152;
    float* bufN = resT + 2097152;                 // fp32 xn (NBL*D) / bf16 delta (NBL*DI)
    bf16*  XZ16 = (bf16*)(bufN + 2097152);        // NBL*4096
    bf16*  U16  = XZ16 + (size_t)NBL * 4096;      // NBL*2048
    float* XD   = (float*)(U16 + (size_t)NBL * 2048); // NBL*96

    // quarter views of XZ16 (NBL*1024 each, contiguous)
    bf16* q0 = XZ16;
    bf16* q1 = XZ16 + 1 * 2097152;
    bf16* q2 = XZ16 + 2 * 2097152;
    bf16* q3 = XZ16 + 3 * 2097152;
    bf16* u0 = U16;
    bf16* u1 = U16 + 2097152;

    const void* x        = d_in[0];
    const void* m_norm   = d_in[1];
    const void* m_Win    = d_in[2];
    const void* m_conv_w = d_in[3];
    const void* m_conv_b = d_in[4];
    const void* m_Wx     = d_in[5];
    const void* m_Wdt    = d_in[6];
    const void* m_bdt    = d_in[7];
    const void* m_Alog   = d_in[8];
    const void* m_D      = d_in[9];
    const void* m_Wout   = d_in[10];
    const void* r_norm   = d_in[11];
    const void* r_mu     = d_in[12];
    const void* r_Wr     = d_in[13];
    const void* r_Wk     = d_in[14];
    const void* r_Wv     = d_in[15];
    const void* r_Wo     = d_in[16];
    const void* r_wlog   = d_in[17];
    const void* r_u      = d_in[18];
    const void* a_Wq     = d_in[19];
    const void* a_bq     = d_in[20];
    const void* a_Wk     = d_in[21];
    const void* a_bk     = d_in[22];
    const void* a_Wv     = d_in[23];
    const void* a_bv     = d_in[24];
    const void* a_Wo     = d_in[25];
    const void* a_bo     = d_in[26];
    const void* f_W      = d_in[27];
    const void* f_b      = d_in[28];

    auto gemm = [&](const void* A, int lda, int aDt, const void* W, long woff,
                    const void* bias, long boff, int hasBias,
                    void* C, int ldc, int cDt, int N, int K, int act, int acc) {
        dim3 g((N + BN - 1) / BN, NBL / BM);
        gemm_k<<<g, 256, 0, stream>>>(A, lda, aDt, W, woff, bias, boff, hasBias,
                                      C, ldc, cDt, N, K, act, acc, flag);
    };

    detect_k<<<1, 64, 0, stream>>>(x, flag);
    cast3_k<<<8192, 256, 0, stream>>>(x, resM, resR, resT, flag);

    // ---------------- Mamba branch ----------------
    for (int i = 0; i < NM_; ++i) {
        rmsnorm_k<<<NBL, 256, 0, stream>>>(resM, m_norm, (long)i * D_, bufN, flag);
        gemm(bufN, D_, 0, m_Win, (long)i * D_ * 2 * DI_, nullptr, 0, 0,
             XZ16, 2 * DI_, 1, 2 * DI_, D_, 0, 0);
        conv_silu_k<<<16384, 256, 0, stream>>>(XZ16, m_conv_w, (long)i * KC_ * DI_,
                                               m_conv_b, (long)i * DI_, U16, flag);
        gemm(U16, DI_, 1, m_Wx, (long)i * DI_ * 96, nullptr, 0, 0,
             XD, 96, 0, 96, DI_, 0, 0);
        gemm(XD, 96, 0, m_Wdt, (long)i * DTR_ * DI_, m_bdt, (long)i * DI_, 1,
             bufN, DI_, 1, DI_, DTR_, 1 /*softplus*/, 0);
        mamba_scan_k<<<B_ * DI_, 256, 0, stream>>>(U16, (const bf16*)bufN, XD, XZ16,
            m_Alog, (long)i * DI_ * DS_, m_D, (long)i * DI_, flag);
        gemm(XZ16, 2 * DI_, 1, m_Wout, (long)i * DI_ * D_, nullptr, 0, 0,
             resM, D_, 0, D_, DI_, 0, 1 /*acc*/);
    }

    // ---------------- RWKV branch ----------------
    for (int i = 0; i < NR_; ++i) {
        rmsnorm_k<<<NBL, 256, 0, stream>>>(resR, r_norm, (long)i * D_, bufN, flag);
        rwkv_mix_k<<<8192, 256, 0, stream>>>(bufN, r_mu, (long)i * 3 * D_,
                                             q0, q1, q2, flag);
        gemm(q0, D_, 1, r_Wr, (long)i * D_ * D_, nullptr, 0, 0, u0, D_, 1, D_, D_, 0, 0);
        gemm(q1, D_, 1, r_Wk, (long)i * D_ * D_, nullptr, 0, 0, u1, D_, 1, D_, D_, 0, 0);
        gemm(q2, D_, 1, r_Wv, (long)i * D_ * D_, nullptr, 0, 0, q3, D_, 1, D_, D_, 0, 0);
        rwkv_scan_k<<<B_ * HR_ * DHR_, RW_NCH * 64, 0, stream>>>(u0, u1, q3,
            r_wlog, (long)i * HR_ * DHR_, r_u, (long)i * HR_ * DHR_, q0, flag);
        gemm(q0, D_, 1, r_Wo, (long)i * D_ * D_, nullptr, 0, 0, resR, D_, 0, D_, D_, 0, 1);
    }

    // ---------------- MHA branch (no norm, no residual) ----------------
    for (int i = 0; i < NT_; ++i) {
        gemm(resT, D_, 0, a_Wq, (long)i * D_ * HA_ * DHA_, a_bq, (long)i * HA_ * DHA_, 1,
             u0, D_, 1, D_, D_, 0, 0);
        gemm(resT, D_, 0, a_Wk, (long)i * D_ * HA_ * DHA_, a_bk, (long)i * HA_ * DHA_, 1,
             u1, D_, 1, D_, D_, 0, 0);
        gemm(resT, D_, 0, a_Wv, (long)i * D_ * HA_ * DHA_, a_bv, (long)i * HA_ * DHA_, 1,
             q3, D_, 1, D_, D_, 0, 0);
        mha_attn_k<<<dim3(L_ / 256, HA_, B_), 256, 0, stream>>>(u0, u1, q3, q0);
        gemm(q0, D_, 1, a_Wo, (long)i * HA_ * DHA_ * D_, a_bo, (long)i * D_, 1,
             resT, D_, 0, D_, HA_ * DHA_, 0, 0 /*no residual*/);
    }

    // ---------------- combine + softmax ----------------
    final_k<<<NBL, 256, 0, stream>>>(resM, resR, resT, f_W, f_b, out, flag);
}

// Round 3
// 4957.670 us; speedup vs baseline: 2.7098x; 1.8539x over previous
//
#include <hip/hip_runtime.h>
#include <hip/hip_bf16.h>
#include <cstddef>

#define D_   1024
#define DI_  2048
#define DS_  16
#define DTR_ 64
#define KC_  4
#define HR_  16
#define DHR_ 64
#define HA_  32
#define DHA_ 32
#define NM_  6
#define NR_  4
#define NT_  2
#define B_   2
#define L_   1024
#define NBL  (B_*L_)   // 2048 rows

typedef __hip_bfloat16 bf16;
typedef __attribute__((ext_vector_type(8))) short short8v;   // 8 bf16 (4 VGPRs)
typedef __attribute__((ext_vector_type(4))) float float4v;   // MFMA C/D frag

__device__ __forceinline__ float bfbits2f(unsigned short u) {
    return __uint_as_float(((unsigned int)u) << 16);
}
__device__ __forceinline__ float b2f(bf16 x) { return __bfloat162float(x); }
__device__ __forceinline__ unsigned short f2bfbits(float f) {
    bf16 h = __float2bfloat16(f);
    return *reinterpret_cast<unsigned short*>(&h);
}
// dtype-dispatched model-input load: bf==1 -> bf16, bf==0 -> fp32
__device__ __forceinline__ float ldf(const void* p, long i, int bf) {
    if (bf) return bfbits2f(((const unsigned short*)p)[i]);
    return ((const float*)p)[i];
}
__device__ __forceinline__ float softplus_f(float x) {
    return x > 20.f ? x : log1pf(__expf(x));
}
__device__ __forceinline__ float silu_f(float x) {
    return x / (1.f + __expf(-x));
}

// ---------------------------------------------------------------------------
// Diagnostic writer (fp32 out): zeros the output, writes a code into out[0].
// ---------------------------------------------------------------------------
__global__ __launch_bounds__(256) void diag_k(float* __restrict__ out, float code)
{
    const int idx = blockIdx.x * 256 + threadIdx.x;
    if (idx < NBL * 3) out[idx] = (idx == 0 ? code : 0.f);
}

// ---------------------------------------------------------------------------
// Input dtype detection (1 wave).
// ---------------------------------------------------------------------------
__global__ __launch_bounds__(64) void detect_k(const void* __restrict__ x,
                                               int* __restrict__ flag)
{
    const unsigned short* u = (const unsigned short*)x;
    int local = 0;
    for (int i = threadIdx.x; i < 1024; i += 64) {
        const float av = fabsf(bfbits2f(u[i]));
        if (!(av < 1e6f)) local = 1;   // catches huge and NaN
    }
    const unsigned long long b = __ballot(local);
    if (threadIdx.x == 0) flag[0] = b ? 0 : 1;  // 1 => inputs are bf16
}

// ---------------------------------------------------------------------------
// MFMA GEMM: C[M,N] = act(A[M,K] @ W[K,N] + bias) (+ C if acc, fp32 C only)
// A: fp32 or bf16 (aDt). W/bias: model dtype (runtime flag). C: fp32 or bf16.
// Both operands cast to bf16; mfma_f32_16x16x32_bf16; fp32 accumulate.
// Tile 64x64, TK=64. 4 waves, each a 32x32 sub-tile (2x2 fragments).
// A staged [row][k]; B staged TRANSPOSED [col][k] so both frag loads are
// contiguous ds_read_b128.  LDT=72 (+8 pad) keeps b128 at bank BW floor.
// Requires: M % 64 == 0, K % 64 == 0 (all call sites satisfy).
// ---------------------------------------------------------------------------
#define BM 64
#define BN 64
#define TK 64
#define LDT 72

__global__ __launch_bounds__(256) void gemm_k(
    const void* __restrict__ A, int lda, int aDt,
    const void* __restrict__ W, long woff,
    const void* __restrict__ bias, long boff, int hasBias,
    void* __restrict__ C, int ldc, int cDt,
    int N, int K, int act, int acc,
    const int* __restrict__ flagp)
{
    const int bf = *flagp;
    __shared__ short As[BM * LDT];
    __shared__ short Bs[BN * LDT];
    const int bm = blockIdx.y * BM;
    const int bn = blockIdx.x * BN;
    const int tid = threadIdx.x;
    const int lane = tid & 63;
    const int wid = tid >> 6;
    const int wr = wid >> 1, wc = wid & 1;

    // staging indices
    const int sa_row = tid >> 2;            // 0..63
    const int sa_kq  = (tid & 3) << 4;      // 0,16,32,48
    const int sb_col = tid & 63;            // 0..63 (wave-coalesced in n)
    const int sb_kq  = (tid >> 6) << 4;     // 0,16,32,48
    const int sb_gn  = bn + sb_col;

    float4v accv[2][2] = {};

    for (int k0 = 0; k0 < K; k0 += TK) {
        // ---- stage A tile (64 rows x 64 k) ----
        {
            short8v a0, a1;
            const size_t aoff = (size_t)(bm + sa_row) * lda + k0 + sa_kq;
            if (aDt) {
                a0 = *(const short8v*)((const unsigned short*)A + aoff);
                a1 = *(const short8v*)((const unsigned short*)A + aoff + 8);
            } else {
                const float* ap = (const float*)A + aoff;
                const float4 v0 = *(const float4*)(ap + 0);
                const float4 v1 = *(const float4*)(ap + 4);
                const float4 v2 = *(const float4*)(ap + 8);
                const float4 v3 = *(const float4*)(ap + 12);
                a0[0]=f2bfbits(v0.x); a0[1]=f2bfbits(v0.y); a0[2]=f2bfbits(v0.z); a0[3]=f2bfbits(v0.w);
                a0[4]=f2bfbits(v1.x); a0[5]=f2bfbits(v1.y); a0[6]=f2bfbits(v1.z); a0[7]=f2bfbits(v1.w);
                a1[0]=f2bfbits(v2.x); a1[1]=f2bfbits(v2.y); a1[2]=f2bfbits(v2.z); a1[3]=f2bfbits(v2.w);
                a1[4]=f2bfbits(v3.x); a1[5]=f2bfbits(v3.y); a1[6]=f2bfbits(v3.z); a1[7]=f2bfbits(v3.w);
            }
            *(short8v*)&As[sa_row * LDT + sa_kq + 0] = a0;
            *(short8v*)&As[sa_row * LDT + sa_kq + 8] = a1;
        }
        // ---- stage B tile transposed: Bs[col][k] (64 cols x 64 k) ----
        {
            short8v b0, b1;
            #pragma unroll
            for (int j = 0; j < 8; ++j) { b0[j] = 0; b1[j] = 0; }
            if (sb_gn < N) {
                const long wbase = woff + (long)(k0 + sb_kq) * N + sb_gn;
                if (bf) {
                    const unsigned short* wp = (const unsigned short*)W;
                    #pragma unroll
                    for (int j = 0; j < 8; ++j) {
                        b0[j] = (short)wp[wbase + (long)j * N];
                        b1[j] = (short)wp[wbase + (long)(j + 8) * N];
                    }
                } else {
                    const float* wp = (const float*)W;
                    #pragma unroll
                    for (int j = 0; j < 8; ++j) {
                        b0[j] = (short)f2bfbits(wp[wbase + (long)j * N]);
                        b1[j] = (short)f2bfbits(wp[wbase + (long)(j + 8) * N]);
                    }
                }
            }
            *(short8v*)&Bs[sb_col * LDT + sb_kq + 0] = b0;
            *(short8v*)&Bs[sb_col * LDT + sb_kq + 8] = b1;
        }
        __syncthreads();
        // ---- MFMA: 8 per wave per K-tile ----
        {
            const int r  = lane & 15;
            const int kb = (lane >> 4) << 3;   // 0,8,16,24
            #pragma unroll
            for (int ks = 0; ks < TK; ks += 32) {
                const int kg = ks + kb;
                const short8v a0 = *(const short8v*)&As[(wr*32 +      r) * LDT + kg];
                const short8v a1 = *(const short8v*)&As[(wr*32 + 16 + r) * LDT + kg];
                const short8v b0 = *(const short8v*)&Bs[(wc*32 +      r) * LDT + kg];
                const short8v b1 = *(const short8v*)&Bs[(wc*32 + 16 + r) * LDT + kg];
                accv[0][0] = __builtin_amdgcn_mfma_f32_16x16x32_bf16(a0, b0, accv[0][0], 0, 0, 0);
                accv[0][1] = __builtin_amdgcn_mfma_f32_16x16x32_bf16(a0, b1, accv[0][1], 0, 0, 0);
                accv[1][0] = __builtin_amdgcn_mfma_f32_16x16x32_bf16(a1, b0, accv[1][0], 0, 0, 0);
                accv[1][1] = __builtin_amdgcn_mfma_f32_16x16x32_bf16(a1, b1, accv[1][1], 0, 0, 0);
            }
        }
        __syncthreads();
    }

    // ---- epilogue: C/D layout col=lane&15, row=(lane>>4)*4+j (m89) ----
    const int crow0 = bm + wr * 32 + ((lane >> 4) << 2);
    const int ccol0 = bn + wc * 32 + (lane & 15);
    #pragma unroll
    for (int ni = 0; ni < 2; ++ni) {
        const int col = ccol0 + ni * 16;
        if (col < N) {
            const float bsv = hasBias ? ldf(bias, boff + col, bf) : 0.f;
            #pragma unroll
            for (int mi = 0; mi < 2; ++mi) {
                #pragma unroll
                for (int j = 0; j < 4; ++j) {
                    const int row = crow0 + mi * 16 + j;
                    float r = accv[mi][ni][j] + bsv;
                    if (act == 1) r = softplus_f(r);
                    if (cDt) {
                        ((bf16*)C)[(size_t)row * ldc + col] = __float2bfloat16(r);
                    } else {
                        float* cp = (float*)C + (size_t)row * ldc + col;
                        if (acc) r += *cp;
                        *cp = r;
                    }
                }
            }
        }
    }
}

// ---------------------------------------------------------------------------
__global__ __launch_bounds__(256) void cast3_k(const void* __restrict__ x,
    float* __restrict__ a, float* __restrict__ b, float* __restrict__ c,
    const int* __restrict__ flagp)
{
    const int bf = *flagp;
    const int idx = blockIdx.x * 256 + threadIdx.x;
    const float v = ldf(x, idx, bf);
    a[idx] = v; b[idx] = v; c[idx] = v;
}

// ---------------------------------------------------------------------------
__global__ __launch_bounds__(256) void rmsnorm_k(const float* __restrict__ x,
    const void* __restrict__ wgt, long woff, float* __restrict__ out,
    const int* __restrict__ flagp)
{
    const int bf = *flagp;
    const int row = blockIdx.x;
    const float* xr = x + (size_t)row * D_;
    float ss = 0.f;
    for (int i = threadIdx.x; i < D_; i += 256) { const float v = xr[i]; ss = fmaf(v, v, ss); }
    #pragma unroll
    for (int msk = 1; msk < 64; msk <<= 1) ss += __shfl_xor(ss, msk);
    __shared__ float red[4];
    if ((threadIdx.x & 63) == 0) red[threadIdx.x >> 6] = ss;
    __syncthreads();
    ss = red[0] + red[1] + red[2] + red[3];
    const float scale = rsqrtf(ss * (1.f / D_) + 1e-6f);
    float* orow = out + (size_t)row * D_;
    for (int i = threadIdx.x; i < D_; i += 256)
        orow[i] = xr[i] * scale * ldf(wgt, woff + i, bf);
}

// ---------------------------------------------------------------------------
// Depthwise causal conv (K=4) + SiLU. xc = cols [0,DI) of xz16 (stride 2*DI).
// ---------------------------------------------------------------------------
__global__ __launch_bounds__(256) void conv_silu_k(const bf16* __restrict__ xz,
    const void* __restrict__ cw, long cwoff, const void* __restrict__ cb, long cboff,
    bf16* __restrict__ out, const int* __restrict__ flagp)
{
    const int bf = *flagp;
    const int idx = blockIdx.x * 256 + threadIdx.x;
    const int c = idx & (DI_ - 1);
    const int l = (idx >> 11) & (L_ - 1);
    const int b = idx >> 21;
    float acc = ldf(cb, cboff + c, bf);
    #pragma unroll
    for (int j = 0; j < KC_; ++j) {
        const int ls = l - (KC_ - 1) + j;
        if (ls >= 0)
            acc = fmaf(b2f(xz[((size_t)(b * L_ + ls)) * (2 * DI_) + c]),
                       ldf(cw, cwoff + j * DI_ + c, bf), acc);
    }
    out[idx] = __float2bfloat16(silu_f(acc));
}

// ---------------------------------------------------------------------------
// Mamba selective scan — chunk-parallel (linear recurrence is associative).
// ---------------------------------------------------------------------------
#define MS_NCH 16
#define MS_CH  (L_ / MS_NCH)   // 64

__global__ __launch_bounds__(256) void mamba_scan_k(
    const bf16* __restrict__ u, const bf16* __restrict__ dlt,
    const float* __restrict__ xdbl, bf16* __restrict__ xz,
    const void* __restrict__ Alog, long aoff, const void* __restrict__ Dp, long doff,
    const int* __restrict__ flagp)
{
    const int bf = *flagp;
    const int bid = blockIdx.x;            // B*DI = 4096
    const int d = bid & (DI_ - 1);
    const int b = bid >> 11;
    const int s = threadIdx.x & (DS_ - 1);
    const int c = threadIdx.x >> 4;        // chunk 0..15
    const float Av = -__expf(ldf(Alog, aoff + d * DS_ + s, bf));
    const float Dv = ldf(Dp, doff + d, bf);

    __shared__ float Pl[MS_NCH][DS_];
    __shared__ float Sl[MS_NCH][DS_];

    const int l0 = c * MS_CH;

    // pass 1: chunk-local (P, S)
    float P = 1.f, S = 0.f;
    for (int i = 0; i < MS_CH; ++i) {
        const size_t row = (size_t)(b * L_ + l0 + i);
        const float ut = b2f(u[row * DI_ + d]);
        const float dt = b2f(dlt[row * DI_ + d]);
        const float Bv = xdbl[row * 96 + 64 + s];
        const float dA = __expf(dt * Av);
        P *= dA;
        S = fmaf(S, dA, dt * ut * Bv);
    }
    Pl[c][s] = P; Sl[c][s] = S;
    __syncthreads();

    // prefix combine: h at this chunk's start
    float hs = 0.f;
    for (int cc = 0; cc < c; ++cc) hs = fmaf(hs, Pl[cc][s], Sl[cc][s]);

    // pass 2: rescan with true h0, reduce over s, write y
    for (int i = 0; i < MS_CH; ++i) {
        const size_t row = (size_t)(b * L_ + l0 + i);
        const float ut = b2f(u[row * DI_ + d]);
        const float dt = b2f(dlt[row * DI_ + d]);
        const float Bv = xdbl[row * 96 + 64 + s];
        const float Cv = xdbl[row * 96 + 80 + s];
        const float dA = __expf(dt * Av);
        hs = fmaf(hs, dA, dt * ut * Bv);
        float yp = hs * Cv;
        yp += __shfl_xor(yp, 1, 16);
        yp += __shfl_xor(yp, 2, 16);
        yp += __shfl_xor(yp, 4, 16);
        yp += __shfl_xor(yp, 8, 16);
        if (s == 0) {
            const float z = b2f(xz[row * (2 * DI_) + DI_ + d]);
            xz[row * (2 * DI_) + d] = __float2bfloat16((yp + Dv * ut) * silu_f(z));
        }
    }
}

// ---------------------------------------------------------------------------
__global__ __launch_bounds__(256) void rwkv_mix_k(const float* __restrict__ xn,
    const void* __restrict__ mu, long muoff, bf16* __restrict__ o0,
    bf16* __restrict__ o1, bf16* __restrict__ o2, const int* __restrict__ flagp)
{
    const int bf = *flagp;
    const int idx = blockIdx.x * 256 + threadIdx.x;
    const int d = idx & (D_ - 1);
    const int l = (idx >> 10) & (L_ - 1);
    const float cur = xn[idx];
    const float prev = (l > 0) ? xn[idx - D_] : 0.f;
    const float m0 = ldf(mu, muoff + d, bf);
    const float m1 = ldf(mu, muoff + D_ + d, bf);
    const float m2 = ldf(mu, muoff + 2 * D_ + d, bf);
    o0[idx] = __float2bfloat16(cur * m0 + prev * (1.f - m0));
    o1[idx] = __float2bfloat16(cur * m1 + prev * (1.f - m1));
    o2[idx] = __float2bfloat16(cur * m2 + prev * (1.f - m2));
}

// ---------------------------------------------------------------------------
// RWKV scan — chunk-parallel (constant w => chunk carry in closed form).
// ---------------------------------------------------------------------------
#define RW_NCH 16
#define RW_CH  (L_ / RW_NCH)   // 64

__global__ __launch_bounds__(1024) void rwkv_scan_k(const bf16* __restrict__ R,
    const bf16* __restrict__ Kb, const bf16* __restrict__ V,
    const void* __restrict__ wlog, long woff, const void* __restrict__ uu, long uoff,
    bf16* __restrict__ Y, const int* __restrict__ flagp)
{
    const int bf = *flagp;
    const int bid = blockIdx.x;           // B*HR*DHR = 2048
    const int v = bid & (DHR_ - 1);
    const int h = (bid >> 6) & (HR_ - 1);
    const int b = bid >> 10;
    const int k = threadIdx.x & 63;
    const int c = threadIdx.x >> 6;       // chunk 0..15
    const float ew = __expf(ldf(wlog, woff + h * DHR_ + k, bf));
    const float w  = __expf(-ew);
    const float wC = __expf(-ew * (float)RW_CH);   // w^CH
    const float uv = ldf(uu, uoff + h * DHR_ + k, bf);

    __shared__ float Se[RW_NCH][64];

    const int l0 = c * RW_CH;

    // pass 1: chunk-local S_end (S0 = 0)
    float S = 0.f;
    for (int i = 0; i < RW_CH; ++i) {
        const size_t off = ((size_t)(b * L_ + l0 + i)) * D_ + h * DHR_;
        const float kk = b2f(Kb[off + k]);
        const float vt = b2f(V[off + v]);
        S = fmaf(w, S, kk * vt);
    }
    Se[c][k] = S;
    __syncthreads();

    // prefix: S at this chunk's start
    S = 0.f;
    for (int cc = 0; cc < c; ++cc) S = fmaf(wC, S, Se[cc][k]);

    // pass 2: rescan with true S0, reduce over k, write y
    for (int i = 0; i < RW_CH; ++i) {
        const size_t off = ((size_t)(b * L_ + l0 + i)) * D_ + h * DHR_;
        const float r  = b2f(R[off + k]);
        const float kk = b2f(Kb[off + k]);
        const float vt = b2f(V[off + v]);
        const float kv = kk * vt;
        float yp = r * fmaf(uv, kv, S);
        S = fmaf(w, S, kv);
        yp += __shfl_xor(yp, 1);
        yp += __shfl_xor(yp, 2);
        yp += __shfl_xor(yp, 4);
        yp += __shfl_xor(yp, 8);
        yp += __shfl_xor(yp, 16);
        yp += __shfl_xor(yp, 32);
        if (k == 0) Y[off + v] = __float2bfloat16(yp);
    }
}

// ---------------------------------------------------------------------------
// MHA flash attention, thread per query row, bf16 Q/K/V/O.
// ---------------------------------------------------------------------------
__global__ __launch_bounds__(256) void mha_attn_k(const bf16* __restrict__ Q,
    const bf16* __restrict__ Kx, const bf16* __restrict__ V, bf16* __restrict__ O)
{
    const int b = blockIdx.z, h = blockIdx.y;
    const int ql = blockIdx.x * 256 + threadIdx.x;
    __shared__ float Ks[32][33];
    __shared__ float Vs[32][33];
    float q[32], o[32];
    #pragma unroll
    for (int d = 0; d < 32; ++d) o[d] = 0.f;
    float mrun = -1e30f, lsum = 0.f;
    const size_t qoff = ((size_t)(b * L_ + ql)) * D_ + h * DHA_;
    #pragma unroll
    for (int d = 0; d < 32; ++d) q[d] = b2f(Q[qoff + d]) * 0.1767766952966369f;

    for (int kt = 0; kt < L_; kt += 32) {
        __syncthreads();
        {
            const int r = threadIdx.x >> 3;
            const int c = (threadIdx.x & 7) << 2;
            const size_t koff = ((size_t)(b * L_ + kt + r)) * D_ + h * DHA_ + c;
            const ushort4 k4 = *(const ushort4*)((const unsigned short*)Kx + koff);
            Ks[r][c + 0] = bfbits2f(k4.x); Ks[r][c + 1] = bfbits2f(k4.y);
            Ks[r][c + 2] = bfbits2f(k4.z); Ks[r][c + 3] = bfbits2f(k4.w);
            const ushort4 v4 = *(const ushort4*)((const unsigned short*)V + koff);
            Vs[r][c + 0] = bfbits2f(v4.x); Vs[r][c + 1] = bfbits2f(v4.y);
            Vs[r][c + 2] = bfbits2f(v4.z); Vs[r][c + 3] = bfbits2f(v4.w);
        }
        __syncthreads();
        for (int j = 0; j < 32; ++j) {
            float s = 0.f;
            #pragma unroll
            for (int d = 0; d < 32; ++d) s = fmaf(q[d], Ks[j][d], s);
            const float mn = fmaxf(mrun, s);
            const float corr = __expf(mrun - mn);
            const float p = __expf(s - mn);
            lsum = lsum * corr + p;
            #pragma unroll
            for (int d = 0; d < 32; ++d) o[d] = o[d] * corr + p * Vs[j][d];
            mrun = mn;
        }
    }
    const float inv = 1.f / lsum;
    #pragma unroll
    for (int d = 0; d < 32; ++d) O[qoff + d] = __float2bfloat16(o[d] * inv);
}

// ---------------------------------------------------------------------------
// Final: logits = [m,r,t] @ f_W + f_b; softmax over 3; fp32 out.
// ---------------------------------------------------------------------------
__global__ __launch_bounds__(256) void final_k(const float* __restrict__ m,
    const float* __restrict__ r, const float* __restrict__ t,
    const void* __restrict__ fW, const void* __restrict__ fb,
    float* __restrict__ out, const int* __restrict__ flagp)
{
    const int bf = *flagp;
    const int row = blockIdx.x;
    float p0 = 0.f, p1 = 0.f, p2 = 0.f;
    for (int i = threadIdx.x; i < 3 * D_; i += 256) {
        float v;
        if (i < D_)          v = m[(size_t)row * D_ + i];
        else if (i < 2 * D_) v = r[(size_t)row * D_ + i - D_];
        else                 v = t[(size_t)row * D_ + i - 2 * D_];
        p0 = fmaf(v, ldf(fW, (long)i * 3 + 0, bf), p0);
        p1 = fmaf(v, ldf(fW, (long)i * 3 + 1, bf), p1);
        p2 = fmaf(v, ldf(fW, (long)i * 3 + 2, bf), p2);
    }
    #pragma unroll
    for (int msk = 1; msk < 64; msk <<= 1) {
        p0 += __shfl_xor(p0, msk);
        p1 += __shfl_xor(p1, msk);
        p2 += __shfl_xor(p2, msk);
    }
    __shared__ float red[4][3];
    if ((threadIdx.x & 63) == 0) {
        const int w = threadIdx.x >> 6;
        red[w][0] = p0; red[w][1] = p1; red[w][2] = p2;
    }
    __syncthreads();
    if (threadIdx.x == 0) {
        const float l0 = red[0][0] + red[1][0] + red[2][0] + red[3][0] + ldf(fb, 0, bf);
        const float l1 = red[0][1] + red[1][1] + red[2][1] + red[3][1] + ldf(fb, 1, bf);
        const float l2 = red[0][2] + red[1][2] + red[2][2] + red[3][2] + ldf(fb, 2, bf);
        const float mx = fmaxf(l0, fmaxf(l1, l2));
        const float e0 = __expf(l0 - mx), e1 = __expf(l1 - mx), e2 = __expf(l2 - mx);
        const float inv = 1.f / (e0 + e1 + e2);
        out[row * 3 + 0] = e0 * inv;
        out[row * 3 + 1] = e1 * inv;
        out[row * 3 + 2] = e2 * inv;
    }
}

// ---------------------------------------------------------------------------
extern "C" void kernel_launch(void* const* d_in, const int* in_sizes, int n_in,
                              void* d_out, int out_size, void* d_ws, size_t ws_size,
                              hipStream_t stream)
{
    float* out = (float*)d_out;

    // ---- self-diagnosis: verify input sizes (dict order) -------------------
    static const int expected[29] = {
        2097152, 6144, 25165824, 49152, 12288, 1179648, 786432, 12288,
        196608, 12288, 12582912, 4096, 12288, 4194304, 4194304, 4194304,
        4194304, 4096, 4096, 2097152, 2048, 2097152, 2048, 2097152, 2048,
        2097152, 2048, 9216, 3 };
    int bad = (n_in == 29) ? -1 : 29;
    if (bad < 0)
        for (int i = 0; i < 29; ++i)
            if (in_sizes[i] != expected[i]) { bad = i; break; }
    if (bad >= 0) {
        diag_k<<<24, 256, 0, stream>>>(out, 1000.f + 8.f * bad);
        return;
    }

    // ---- workspace layout (56.8 MB total) ----------------------------------
    const size_t REQ = 64 + 3ull * 8388608 + 8388608 + 16777216 + 8388608 + 786432;
    if (ws_size < REQ) {
        diag_k<<<24, 256, 0, stream>>>(out, 2048.f + (float)(ws_size >> 20));
        return;
    }
    char* base = (char*)d_ws;
    int*   flag = (int*)base;
    float* resM = (float*)(base + 64);
    float* resR = resM + 2097152;
    float* resT = resR + 2097152;
    float* bufN = resT + 2097152;                 // fp32 xn (NBL*D) / bf16 delta (NBL*DI)
    bf16*  XZ16 = (bf16*)(bufN + 2097152);        // NBL*4096
    bf16*  U16  = XZ16 + (size_t)NBL * 4096;      // NBL*2048
    float* XD   = (float*)(U16 + (size_t)NBL * 2048); // NBL*96

    // quarter views of XZ16 (NBL*1024 each, contiguous)
    bf16* q0 = XZ16;
    bf16* q1 = XZ16 + 1 * 2097152;
    bf16* q2 = XZ16 + 2 * 2097152;
    bf16* q3 = XZ16 + 3 * 2097152;
    bf16* u0 = U16;
    bf16* u1 = U16 + 2097152;

    const void* x        = d_in[0];
    const void* m_norm   = d_in[1];
    const void* m_Win    = d_in[2];
    const void* m_conv_w = d_in[3];
    const void* m_conv_b = d_in[4];
    const void* m_Wx     = d_in[5];
    const void* m_Wdt    = d_in[6];
    const void* m_bdt    = d_in[7];
    const void* m_Alog   = d_in[8];
    const void* m_D      = d_in[9];
    const void* m_Wout   = d_in[10];
    const void* r_norm   = d_in[11];
    const void* r_mu     = d_in[12];
    const void* r_Wr     = d_in[13];
    const void* r_Wk     = d_in[14];
    const void* r_Wv     = d_in[15];
    const void* r_Wo     = d_in[16];
    const void* r_wlog   = d_in[17];
    const void* r_u      = d_in[18];
    const void* a_Wq     = d_in[19];
    const void* a_bq     = d_in[20];
    const void* a_Wk     = d_in[21];
    const void* a_bk     = d_in[22];
    const void* a_Wv     = d_in[23];
    const void* a_bv     = d_in[24];
    const void* a_Wo     = d_in[25];
    const void* a_bo     = d_in[26];
    const void* f_W      = d_in[27];
    const void* f_b      = d_in[28];

    auto gemm = [&](const void* A, int lda, int aDt, const void* W, long woff,
                    const void* bias, long boff, int hasBias,
                    void* C, int ldc, int cDt, int N, int K, int act, int acc) {
        dim3 g((N + BN - 1) / BN, NBL / BM);
        gemm_k<<<g, 256, 0, stream>>>(A, lda, aDt, W, woff, bias, boff, hasBias,
                                      C, ldc, cDt, N, K, act, acc, flag);
    };

    detect_k<<<1, 64, 0, stream>>>(x, flag);
    cast3_k<<<8192, 256, 0, stream>>>(x, resM, resR, resT, flag);

    // ---------------- Mamba branch ----------------
    for (int i = 0; i < NM_; ++i) {
        rmsnorm_k<<<NBL, 256, 0, stream>>>(resM, m_norm, (long)i * D_, bufN, flag);
        gemm(bufN, D_, 0, m_Win, (long)i * D_ * 2 * DI_, nullptr, 0, 0,
             XZ16, 2 * DI_, 1, 2 * DI_, D_, 0, 0);
        conv_silu_k<<<16384, 256, 0, stream>>>(XZ16, m_conv_w, (long)i * KC_ * DI_,
                                               m_conv_b, (long)i * DI_, U16, flag);
        gemm(U16, DI_, 1, m_Wx, (long)i * DI_ * 96, nullptr, 0, 0,
             XD, 96, 0, 96, DI_, 0, 0);
        gemm(XD, 96, 0, m_Wdt, (long)i * DTR_ * DI_, m_bdt, (long)i * DI_, 1,
             bufN, DI_, 1, DI_, DTR_, 1 /*softplus*/, 0);
        mamba_scan_k<<<B_ * DI_, 256, 0, stream>>>(U16, (const bf16*)bufN, XD, XZ16,
            m_Alog, (long)i * DI_ * DS_, m_D, (long)i * DI_, flag);
        gemm(XZ16, 2 * DI_, 1, m_Wout, (long)i * DI_ * D_, nullptr, 0, 0,
             resM, D_, 0, D_, DI_, 0, 1 /*acc*/);
    }

    // ---------------- RWKV branch ----------------
    for (int i = 0; i < NR_; ++i) {
        rmsnorm_k<<<NBL, 256, 0, stream>>>(resR, r_norm, (long)i * D_, bufN, flag);
        rwkv_mix_k<<<8192, 256, 0, stream>>>(bufN, r_mu, (long)i * 3 * D_,
                                             q0, q1, q2, flag);
        gemm(q0, D_, 1, r_Wr, (long)i * D_ * D_, nullptr, 0, 0, u0, D_, 1, D_, D_, 0, 0);
        gemm(q1, D_, 1, r_Wk, (long)i * D_ * D_, nullptr, 0, 0, u1, D_, 1, D_, D_, 0, 0);
        gemm(q2, D_, 1, r_Wv, (long)i * D_ * D_, nullptr, 0, 0, q3, D_, 1, D_, D_, 0, 0);
        rwkv_scan_k<<<B_ * HR_ * DHR_, RW_NCH * 64, 0, stream>>>(u0, u1, q3,
            r_wlog, (long)i * HR_ * DHR_, r_u, (long)i * HR_ * DHR_, q0, flag);
        gemm(q0, D_, 1, r_Wo, (long)i * D_ * D_, nullptr, 0, 0, resR, D_, 0, D_, D_, 0, 1);
    }

    // ---------------- MHA branch (no norm, no residual) ----------------
    for (int i = 0; i < NT_; ++i) {
        gemm(resT, D_, 0, a_Wq, (long)i * D_ * HA_ * DHA_, a_bq, (long)i * HA_ * DHA_, 1,
             u0, D_, 1, D_, D_, 0, 0);
        gemm(resT, D_, 0, a_Wk, (long)i * D_ * HA_ * DHA_, a_bk, (long)i * HA_ * DHA_, 1,
             u1, D_, 1, D_, D_, 0, 0);
        gemm(resT, D_, 0, a_Wv, (long)i * D_ * HA_ * DHA_, a_bv, (long)i * HA_ * DHA_, 1,
             q3, D_, 1, D_, D_, 0, 0);
        mha_attn_k<<<dim3(L_ / 256, HA_, B_), 256, 0, stream>>>(u0, u1, q3, q0);
        gemm(q0, D_, 1, a_Wo, (long)i * HA_ * DHA_ * D_, a_bo, (long)i * D_, 1,
             resT, D_, 0, D_, HA_ * DHA_, 0, 0 /*no residual*/);
    }

    // ---------------- combine + softmax ----------------
    final_k<<<NBL, 256, 0, stream>>>(resM, resR, resT, f_W, f_b, out, flag);
}

// Round 4
// 4168.214 us; speedup vs baseline: 3.2231x; 1.1894x over previous
//
#include <hip/hip_runtime.h>
#include <hip/hip_bf16.h>
#include <cstddef>

#define D_   1024
#define DI_  2048
#define DS_  16
#define DTR_ 64
#define KC_  4
#define HR_  16
#define DHR_ 64
#define HA_  32
#define DHA_ 32
#define NM_  6
#define NR_  4
#define NT_  2
#define B_   2
#define L_   1024
#define NBL  (B_*L_)   // 2048 rows

typedef __hip_bfloat16 bf16;
typedef __attribute__((ext_vector_type(8))) short short8v;   // 8 bf16 (4 VGPRs)
typedef __attribute__((ext_vector_type(4))) float float4v;   // MFMA C/D frag

__device__ __forceinline__ float bfbits2f(unsigned short u) {
    return __uint_as_float(((unsigned int)u) << 16);
}
__device__ __forceinline__ float b2f(bf16 x) { return __bfloat162float(x); }
__device__ __forceinline__ unsigned short f2bfbits(float f) {
    bf16 h = __float2bfloat16(f);
    return *reinterpret_cast<unsigned short*>(&h);
}
// dtype-dispatched model-input load: bf==1 -> bf16, bf==0 -> fp32
__device__ __forceinline__ float ldf(const void* p, long i, int bf) {
    if (bf) return bfbits2f(((const unsigned short*)p)[i]);
    return ((const float*)p)[i];
}
__device__ __forceinline__ float softplus_f(float x) {
    return x > 20.f ? x : log1pf(__expf(x));
}
__device__ __forceinline__ float silu_f(float x) {
    return x / (1.f + __expf(-x));
}

// ---------------------------------------------------------------------------
// Diagnostic writer (fp32 out): zeros the output, writes a code into out[0].
// ---------------------------------------------------------------------------
__global__ __launch_bounds__(256) void diag_k(float* __restrict__ out, float code)
{
    const int idx = blockIdx.x * 256 + threadIdx.x;
    if (idx < NBL * 3) out[idx] = (idx == 0 ? code : 0.f);
}

// ---------------------------------------------------------------------------
// Input dtype detection (1 wave).
// ---------------------------------------------------------------------------
__global__ __launch_bounds__(64) void detect_k(const void* __restrict__ x,
                                               int* __restrict__ flag)
{
    const unsigned short* u = (const unsigned short*)x;
    int local = 0;
    for (int i = threadIdx.x; i < 1024; i += 64) {
        const float av = fabsf(bfbits2f(u[i]));
        if (!(av < 1e6f)) local = 1;   // catches huge and NaN
    }
    const unsigned long long b = __ballot(local);
    if (threadIdx.x == 0) flag[0] = b ? 0 : 1;  // 1 => inputs are bf16
}

// ---------------------------------------------------------------------------
// MFMA GEMM: C[M,N] = act(A[M,K] @ W[K,N] + bias) (+ C if acc, fp32 C only)
// Tile 64x64, TK=64. 4 waves, each a 32x32 sub-tile (2x2 fragments).
// ---------------------------------------------------------------------------
#define BM 64
#define BN 64
#define TK 64
#define LDT 72

__global__ __launch_bounds__(256) void gemm_k(
    const void* __restrict__ A, int lda, int aDt,
    const void* __restrict__ W, long woff,
    const void* __restrict__ bias, long boff, int hasBias,
    void* __restrict__ C, int ldc, int cDt,
    int N, int K, int act, int acc,
    const int* __restrict__ flagp)
{
    const int bf = *flagp;
    __shared__ short As[BM * LDT];
    __shared__ short Bs[BN * LDT];
    const int bm = blockIdx.y * BM;
    const int bn = blockIdx.x * BN;
    const int tid = threadIdx.x;
    const int lane = tid & 63;
    const int wid = tid >> 6;
    const int wr = wid >> 1, wc = wid & 1;

    // staging indices
    const int sa_row = tid >> 2;            // 0..63
    const int sa_kq  = (tid & 3) << 4;      // 0,16,32,48
    const int sb_col = tid & 63;            // 0..63 (wave-coalesced in n)
    const int sb_kq  = (tid >> 6) << 4;     // 0,16,32,48
    const int sb_gn  = bn + sb_col;

    float4v accv[2][2] = {};

    for (int k0 = 0; k0 < K; k0 += TK) {
        // ---- stage A tile (64 rows x 64 k) ----
        {
            short8v a0, a1;
            const size_t aoff = (size_t)(bm + sa_row) * lda + k0 + sa_kq;
            if (aDt) {
                a0 = *(const short8v*)((const unsigned short*)A + aoff);
                a1 = *(const short8v*)((const unsigned short*)A + aoff + 8);
            } else {
                const float* ap = (const float*)A + aoff;
                const float4 v0 = *(const float4*)(ap + 0);
                const float4 v1 = *(const float4*)(ap + 4);
                const float4 v2 = *(const float4*)(ap + 8);
                const float4 v3 = *(const float4*)(ap + 12);
                a0[0]=f2bfbits(v0.x); a0[1]=f2bfbits(v0.y); a0[2]=f2bfbits(v0.z); a0[3]=f2bfbits(v0.w);
                a0[4]=f2bfbits(v1.x); a0[5]=f2bfbits(v1.y); a0[6]=f2bfbits(v1.z); a0[7]=f2bfbits(v1.w);
                a1[0]=f2bfbits(v2.x); a1[1]=f2bfbits(v2.y); a1[2]=f2bfbits(v2.z); a1[3]=f2bfbits(v2.w);
                a1[4]=f2bfbits(v3.x); a1[5]=f2bfbits(v3.y); a1[6]=f2bfbits(v3.z); a1[7]=f2bfbits(v3.w);
            }
            *(short8v*)&As[sa_row * LDT + sa_kq + 0] = a0;
            *(short8v*)&As[sa_row * LDT + sa_kq + 8] = a1;
        }
        // ---- stage B tile transposed: Bs[col][k] (64 cols x 64 k) ----
        {
            short8v b0, b1;
            #pragma unroll
            for (int j = 0; j < 8; ++j) { b0[j] = 0; b1[j] = 0; }
            if (sb_gn < N) {
                const long wbase = woff + (long)(k0 + sb_kq) * N + sb_gn;
                if (bf) {
                    const unsigned short* wp = (const unsigned short*)W;
                    #pragma unroll
                    for (int j = 0; j < 8; ++j) {
                        b0[j] = (short)wp[wbase + (long)j * N];
                        b1[j] = (short)wp[wbase + (long)(j + 8) * N];
                    }
                } else {
                    const float* wp = (const float*)W;
                    #pragma unroll
                    for (int j = 0; j < 8; ++j) {
                        b0[j] = (short)f2bfbits(wp[wbase + (long)j * N]);
                        b1[j] = (short)f2bfbits(wp[wbase + (long)(j + 8) * N]);
                    }
                }
            }
            *(short8v*)&Bs[sb_col * LDT + sb_kq + 0] = b0;
            *(short8v*)&Bs[sb_col * LDT + sb_kq + 8] = b1;
        }
        __syncthreads();
        // ---- MFMA: 8 per wave per K-tile ----
        {
            const int r  = lane & 15;
            const int kb = (lane >> 4) << 3;   // 0,8,16,24
            #pragma unroll
            for (int ks = 0; ks < TK; ks += 32) {
                const int kg = ks + kb;
                const short8v a0 = *(const short8v*)&As[(wr*32 +      r) * LDT + kg];
                const short8v a1 = *(const short8v*)&As[(wr*32 + 16 + r) * LDT + kg];
                const short8v b0 = *(const short8v*)&Bs[(wc*32 +      r) * LDT + kg];
                const short8v b1 = *(const short8v*)&Bs[(wc*32 + 16 + r) * LDT + kg];
                accv[0][0] = __builtin_amdgcn_mfma_f32_16x16x32_bf16(a0, b0, accv[0][0], 0, 0, 0);
                accv[0][1] = __builtin_amdgcn_mfma_f32_16x16x32_bf16(a0, b1, accv[0][1], 0, 0, 0);
                accv[1][0] = __builtin_amdgcn_mfma_f32_16x16x32_bf16(a1, b0, accv[1][0], 0, 0, 0);
                accv[1][1] = __builtin_amdgcn_mfma_f32_16x16x32_bf16(a1, b1, accv[1][1], 0, 0, 0);
            }
        }
        __syncthreads();
    }

    // ---- epilogue: C/D layout col=lane&15, row=(lane>>4)*4+j (m89) ----
    const int crow0 = bm + wr * 32 + ((lane >> 4) << 2);
    const int ccol0 = bn + wc * 32 + (lane & 15);
    #pragma unroll
    for (int ni = 0; ni < 2; ++ni) {
        const int col = ccol0 + ni * 16;
        if (col < N) {
            const float bsv = hasBias ? ldf(bias, boff + col, bf) : 0.f;
            #pragma unroll
            for (int mi = 0; mi < 2; ++mi) {
                #pragma unroll
                for (int j = 0; j < 4; ++j) {
                    const int row = crow0 + mi * 16 + j;
                    float r = accv[mi][ni][j] + bsv;
                    if (act == 1) r = softplus_f(r);
                    if (cDt) {
                        ((bf16*)C)[(size_t)row * ldc + col] = __float2bfloat16(r);
                    } else {
                        float* cp = (float*)C + (size_t)row * ldc + col;
                        if (acc) r += *cp;
                        *cp = r;
                    }
                }
            }
        }
    }
}

// ---------------------------------------------------------------------------
__global__ __launch_bounds__(256) void cast3_k(const void* __restrict__ x,
    float* __restrict__ a, float* __restrict__ b, float* __restrict__ c,
    const int* __restrict__ flagp)
{
    const int bf = *flagp;
    const int idx = blockIdx.x * 256 + threadIdx.x;
    const float v = ldf(x, idx, bf);
    a[idx] = v; b[idx] = v; c[idx] = v;
}

// ---------------------------------------------------------------------------
__global__ __launch_bounds__(256) void rmsnorm_k(const float* __restrict__ x,
    const void* __restrict__ wgt, long woff, float* __restrict__ out,
    const int* __restrict__ flagp)
{
    const int bf = *flagp;
    const int row = blockIdx.x;
    const float* xr = x + (size_t)row * D_;
    float ss = 0.f;
    for (int i = threadIdx.x; i < D_; i += 256) { const float v = xr[i]; ss = fmaf(v, v, ss); }
    #pragma unroll
    for (int msk = 1; msk < 64; msk <<= 1) ss += __shfl_xor(ss, msk);
    __shared__ float red[4];
    if ((threadIdx.x & 63) == 0) red[threadIdx.x >> 6] = ss;
    __syncthreads();
    ss = red[0] + red[1] + red[2] + red[3];
    const float scale = rsqrtf(ss * (1.f / D_) + 1e-6f);
    float* orow = out + (size_t)row * D_;
    for (int i = threadIdx.x; i < D_; i += 256)
        orow[i] = xr[i] * scale * ldf(wgt, woff + i, bf);
}

// ---------------------------------------------------------------------------
// Depthwise causal conv (K=4) + SiLU. xc = cols [0,DI) of xz16 (stride 2*DI).
// ---------------------------------------------------------------------------
__global__ __launch_bounds__(256) void conv_silu_k(const bf16* __restrict__ xz,
    const void* __restrict__ cw, long cwoff, const void* __restrict__ cb, long cboff,
    bf16* __restrict__ out, const int* __restrict__ flagp)
{
    const int bf = *flagp;
    const int idx = blockIdx.x * 256 + threadIdx.x;
    const int c = idx & (DI_ - 1);
    const int l = (idx >> 11) & (L_ - 1);
    const int b = idx >> 21;
    float acc = ldf(cb, cboff + c, bf);
    #pragma unroll
    for (int j = 0; j < KC_; ++j) {
        const int ls = l - (KC_ - 1) + j;
        if (ls >= 0)
            acc = fmaf(b2f(xz[((size_t)(b * L_ + ls)) * (2 * DI_) + c]),
                       ldf(cw, cwoff + j * DI_ + c, bf), acc);
    }
    out[idx] = __float2bfloat16(silu_f(acc));
}

// ---------------------------------------------------------------------------
// Mamba selective scan — chunk-parallel (linear recurrence is associative).
// ---------------------------------------------------------------------------
#define MS_NCH 16
#define MS_CH  (L_ / MS_NCH)   // 64

__global__ __launch_bounds__(256) void mamba_scan_k(
    const bf16* __restrict__ u, const bf16* __restrict__ dlt,
    const float* __restrict__ xdbl, bf16* __restrict__ xz,
    const void* __restrict__ Alog, long aoff, const void* __restrict__ Dp, long doff,
    const int* __restrict__ flagp)
{
    const int bf = *flagp;
    const int bid = blockIdx.x;            // B*DI = 4096
    const int d = bid & (DI_ - 1);
    const int b = bid >> 11;
    const int s = threadIdx.x & (DS_ - 1);
    const int c = threadIdx.x >> 4;        // chunk 0..15
    const float Av = -__expf(ldf(Alog, aoff + d * DS_ + s, bf));
    const float Dv = ldf(Dp, doff + d, bf);

    __shared__ float Pl[MS_NCH][DS_];
    __shared__ float Sl[MS_NCH][DS_];

    const int l0 = c * MS_CH;

    // pass 1: chunk-local (P, S)
    float P = 1.f, S = 0.f;
    for (int i = 0; i < MS_CH; ++i) {
        const size_t row = (size_t)(b * L_ + l0 + i);
        const float ut = b2f(u[row * DI_ + d]);
        const float dt = b2f(dlt[row * DI_ + d]);
        const float Bv = xdbl[row * 96 + 64 + s];
        const float dA = __expf(dt * Av);
        P *= dA;
        S = fmaf(S, dA, dt * ut * Bv);
    }
    Pl[c][s] = P; Sl[c][s] = S;
    __syncthreads();

    // prefix combine: h at this chunk's start
    float hs = 0.f;
    for (int cc = 0; cc < c; ++cc) hs = fmaf(hs, Pl[cc][s], Sl[cc][s]);

    // pass 2: rescan with true h0, reduce over s, write y
    for (int i = 0; i < MS_CH; ++i) {
        const size_t row = (size_t)(b * L_ + l0 + i);
        const float ut = b2f(u[row * DI_ + d]);
        const float dt = b2f(dlt[row * DI_ + d]);
        const float Bv = xdbl[row * 96 + 64 + s];
        const float Cv = xdbl[row * 96 + 80 + s];
        const float dA = __expf(dt * Av);
        hs = fmaf(hs, dA, dt * ut * Bv);
        float yp = hs * Cv;
        yp += __shfl_xor(yp, 1, 16);
        yp += __shfl_xor(yp, 2, 16);
        yp += __shfl_xor(yp, 4, 16);
        yp += __shfl_xor(yp, 8, 16);
        if (s == 0) {
            const float z = b2f(xz[row * (2 * DI_) + DI_ + d]);
            xz[row * (2 * DI_) + d] = __float2bfloat16((yp + Dv * ut) * silu_f(z));
        }
    }
}

// ---------------------------------------------------------------------------
__global__ __launch_bounds__(256) void rwkv_mix_k(const float* __restrict__ xn,
    const void* __restrict__ mu, long muoff, bf16* __restrict__ o0,
    bf16* __restrict__ o1, bf16* __restrict__ o2, const int* __restrict__ flagp)
{
    const int bf = *flagp;
    const int idx = blockIdx.x * 256 + threadIdx.x;
    const int d = idx & (D_ - 1);
    const int l = (idx >> 10) & (L_ - 1);
    const float cur = xn[idx];
    const float prev = (l > 0) ? xn[idx - D_] : 0.f;
    const float m0 = ldf(mu, muoff + d, bf);
    const float m1 = ldf(mu, muoff + D_ + d, bf);
    const float m2 = ldf(mu, muoff + 2 * D_ + d, bf);
    o0[idx] = __float2bfloat16(cur * m0 + prev * (1.f - m0));
    o1[idx] = __float2bfloat16(cur * m1 + prev * (1.f - m1));
    o2[idx] = __float2bfloat16(cur * m2 + prev * (1.f - m2));
}

// ---------------------------------------------------------------------------
// RWKV scan — chunk-parallel (constant w => chunk carry in closed form).
// ---------------------------------------------------------------------------
#define RW_NCH 16
#define RW_CH  (L_ / RW_NCH)   // 64

__global__ __launch_bounds__(1024) void rwkv_scan_k(const bf16* __restrict__ R,
    const bf16* __restrict__ Kb, const bf16* __restrict__ V,
    const void* __restrict__ wlog, long woff, const void* __restrict__ uu, long uoff,
    bf16* __restrict__ Y, const int* __restrict__ flagp)
{
    const int bf = *flagp;
    const int bid = blockIdx.x;           // B*HR*DHR = 2048
    const int v = bid & (DHR_ - 1);
    const int h = (bid >> 6) & (HR_ - 1);
    const int b = bid >> 10;
    const int k = threadIdx.x & 63;
    const int c = threadIdx.x >> 6;       // chunk 0..15
    const float ew = __expf(ldf(wlog, woff + h * DHR_ + k, bf));
    const float w  = __expf(-ew);
    const float wC = __expf(-ew * (float)RW_CH);   // w^CH
    const float uv = ldf(uu, uoff + h * DHR_ + k, bf);

    __shared__ float Se[RW_NCH][64];

    const int l0 = c * RW_CH;

    // pass 1: chunk-local S_end (S0 = 0)
    float S = 0.f;
    for (int i = 0; i < RW_CH; ++i) {
        const size_t off = ((size_t)(b * L_ + l0 + i)) * D_ + h * DHR_;
        const float kk = b2f(Kb[off + k]);
        const float vt = b2f(V[off + v]);
        S = fmaf(w, S, kk * vt);
    }
    Se[c][k] = S;
    __syncthreads();

    // prefix: S at this chunk's start
    S = 0.f;
    for (int cc = 0; cc < c; ++cc) S = fmaf(wC, S, Se[cc][k]);

    // pass 2: rescan with true S0, reduce over k, write y
    for (int i = 0; i < RW_CH; ++i) {
        const size_t off = ((size_t)(b * L_ + l0 + i)) * D_ + h * DHR_;
        const float r  = b2f(R[off + k]);
        const float kk = b2f(Kb[off + k]);
        const float vt = b2f(V[off + v]);
        const float kv = kk * vt;
        float yp = r * fmaf(uv, kv, S);
        S = fmaf(w, S, kv);
        yp += __shfl_xor(yp, 1);
        yp += __shfl_xor(yp, 2);
        yp += __shfl_xor(yp, 4);
        yp += __shfl_xor(yp, 8);
        yp += __shfl_xor(yp, 16);
        yp += __shfl_xor(yp, 32);
        if (k == 0) Y[off + v] = __float2bfloat16(yp);
    }
}

// ---------------------------------------------------------------------------
// MHA flash attention — MFMA version.
// Block = (64-q tile, h, b), 4 waves x 16 q-rows.  KV tiles of 64.
// QK^T: A=Q (16x32, K=DHA=32 = one mfma depth), B=K staged natural [n][d].
// Online softmax: C-frag row=(lane>>4)*4+j => per-lane m[4],l[4] replicated
// across each 16-lane group after shfl reduction.  P->bf16 in per-wave LDS,
// PV: A=P from LDS, B=V staged transposed [d][kv].
// Frag layouts identical to gemm_k's (harness-verified).
// ---------------------------------------------------------------------------
#define LDK 40   // Ks row pitch (bf16): 80B, 16B-aligned, 2-way banks (free)
#define LDV 72   // Vt/Ps row pitch (bf16): 144B, 16B-aligned, 2-way banks

__global__ __launch_bounds__(256) void mha_attn_k(const bf16* __restrict__ Q,
    const bf16* __restrict__ Kx, const bf16* __restrict__ V, bf16* __restrict__ O)
{
    const int b = blockIdx.z, h = blockIdx.y;
    const int qt = blockIdx.x;            // 0..15
    const int tid = threadIdx.x;
    const int lane = tid & 63;
    const int wid = tid >> 6;

    __shared__ __align__(16) short Ks[64 * LDK];
    __shared__ __align__(16) short Vt[32 * LDV];
    __shared__ __align__(16) short Ps[4][16 * LDV];

    const int fc  = lane & 15;            // A-row / B-col within fragment
    const int g   = lane >> 4;            // k-octet group; C rows = g*4+j
    const int fk8 = g << 3;               // 0,8,16,24

    const int q0 = qt * 64 + wid * 16;

    // Q fragment (K=32 = full head dim), loaded once
    const size_t qoff = ((size_t)(b * L_ + q0 + fc)) * D_ + h * DHA_ + fk8;
    const short8v qf = *(const short8v*)((const unsigned short*)Q + qoff);

    float4v o0 = {}, o1 = {};
    float m[4] = {-1e30f, -1e30f, -1e30f, -1e30f};
    float l[4] = {0.f, 0.f, 0.f, 0.f};
    const float scale = 0.1767766952966369f;   // 1/sqrt(32)

    // staging indices: thread t covers (row=t>>2, d-octet=(t&3)*8)
    const int sr = tid >> 2;
    const int sc = (tid & 3) << 3;

    for (int kt = 0; kt < L_; kt += 64) {
        __syncthreads();   // all waves done reading previous Ks/Vt
        {
            const size_t koff = ((size_t)(b * L_ + kt + sr)) * D_ + h * DHA_ + sc;
            const short8v k8 = *(const short8v*)((const unsigned short*)Kx + koff);
            *(short8v*)&Ks[sr * LDK + sc] = k8;
            const short8v v8 = *(const short8v*)((const unsigned short*)V + koff);
            #pragma unroll
            for (int j = 0; j < 8; ++j)
                Vt[(sc + j) * LDV + sr] = v8[j];
        }
        __syncthreads();

        // ---- QK^T: 4 mfma over 4 kv-16 sub-tiles ----
        float4v sv[4];
        #pragma unroll
        for (int nt = 0; nt < 4; ++nt) {
            const short8v kf = *(const short8v*)&Ks[(nt * 16 + fc) * LDK + fk8];
            float4v z = {};
            sv[nt] = __builtin_amdgcn_mfma_f32_16x16x32_bf16(qf, kf, z, 0, 0, 0);
        }

        // ---- online softmax (rows g*4+j, cols nt*16+fc) ----
        #pragma unroll
        for (int j = 0; j < 4; ++j) {
            float mt = fmaxf(fmaxf(sv[0][j], sv[1][j]), fmaxf(sv[2][j], sv[3][j])) * scale;
            #pragma unroll
            for (int msk = 1; msk < 16; msk <<= 1) mt = fmaxf(mt, __shfl_xor(mt, msk));
            const float mn = fmaxf(m[j], mt);
            const float corr = __expf(m[j] - mn);
            m[j] = mn;
            float sum = 0.f;
            #pragma unroll
            for (int nt = 0; nt < 4; ++nt) {
                const float p = __expf(fmaf(sv[nt][j], scale, -mn));
                sum += p;
                Ps[wid][(g * 4 + j) * LDV + nt * 16 + fc] = (short)f2bfbits(p);
            }
            #pragma unroll
            for (int msk = 1; msk < 16; msk <<= 1) sum += __shfl_xor(sum, msk);
            l[j] = l[j] * corr + sum;
            o0[j] *= corr;
            o1[j] *= corr;
        }

        // ---- PV: O += P(16x64) . V(64x32), 2 k-chunks x 2 d-tiles ----
        #pragma unroll
        for (int kc = 0; kc < 2; ++kc) {
            const short8v pf = *(const short8v*)&Ps[wid][fc * LDV + kc * 32 + fk8];
            const short8v v0 = *(const short8v*)&Vt[(fc) * LDV + kc * 32 + fk8];
            const short8v v1 = *(const short8v*)&Vt[(16 + fc) * LDV + kc * 32 + fk8];
            o0 = __builtin_amdgcn_mfma_f32_16x16x32_bf16(pf, v0, o0, 0, 0, 0);
            o1 = __builtin_amdgcn_mfma_f32_16x16x32_bf16(pf, v1, o1, 0, 0, 0);
        }
    }

    // ---- epilogue ----
    #pragma unroll
    for (int j = 0; j < 4; ++j) {
        const float inv = 1.f / l[j];
        const size_t ooff = ((size_t)(b * L_ + q0 + g * 4 + j)) * D_ + h * DHA_;
        O[ooff + fc]      = __float2bfloat16(o0[j] * inv);
        O[ooff + 16 + fc] = __float2bfloat16(o1[j] * inv);
    }
}

// ---------------------------------------------------------------------------
// Final: logits = [m,r,t] @ f_W + f_b; softmax over 3; fp32 out.
// ---------------------------------------------------------------------------
__global__ __launch_bounds__(256) void final_k(const float* __restrict__ m,
    const float* __restrict__ r, const float* __restrict__ t,
    const void* __restrict__ fW, const void* __restrict__ fb,
    float* __restrict__ out, const int* __restrict__ flagp)
{
    const int bf = *flagp;
    const int row = blockIdx.x;
    float p0 = 0.f, p1 = 0.f, p2 = 0.f;
    for (int i = threadIdx.x; i < 3 * D_; i += 256) {
        float v;
        if (i < D_)          v = m[(size_t)row * D_ + i];
        else if (i < 2 * D_) v = r[(size_t)row * D_ + i - D_];
        else                 v = t[(size_t)row * D_ + i - 2 * D_];
        p0 = fmaf(v, ldf(fW, (long)i * 3 + 0, bf), p0);
        p1 = fmaf(v, ldf(fW, (long)i * 3 + 1, bf), p1);
        p2 = fmaf(v, ldf(fW, (long)i * 3 + 2, bf), p2);
    }
    #pragma unroll
    for (int msk = 1; msk < 64; msk <<= 1) {
        p0 += __shfl_xor(p0, msk);
        p1 += __shfl_xor(p1, msk);
        p2 += __shfl_xor(p2, msk);
    }
    __shared__ float red[4][3];
    if ((threadIdx.x & 63) == 0) {
        const int w = threadIdx.x >> 6;
        red[w][0] = p0; red[w][1] = p1; red[w][2] = p2;
    }
    __syncthreads();
    if (threadIdx.x == 0) {
        const float l0 = red[0][0] + red[1][0] + red[2][0] + red[3][0] + ldf(fb, 0, bf);
        const float l1 = red[0][1] + red[1][1] + red[2][1] + red[3][1] + ldf(fb, 1, bf);
        const float l2 = red[0][2] + red[1][2] + red[2][2] + red[3][2] + ldf(fb, 2, bf);
        const float mx = fmaxf(l0, fmaxf(l1, l2));
        const float e0 = __expf(l0 - mx), e1 = __expf(l1 - mx), e2 = __expf(l2 - mx);
        const float inv = 1.f / (e0 + e1 + e2);
        out[row * 3 + 0] = e0 * inv;
        out[row * 3 + 1] = e1 * inv;
        out[row * 3 + 2] = e2 * inv;
    }
}

// ---------------------------------------------------------------------------
extern "C" void kernel_launch(void* const* d_in, const int* in_sizes, int n_in,
                              void* d_out, int out_size, void* d_ws, size_t ws_size,
                              hipStream_t stream)
{
    float* out = (float*)d_out;

    // ---- self-diagnosis: verify input sizes (dict order) -------------------
    static const int expected[29] = {
        2097152, 6144, 25165824, 49152, 12288, 1179648, 786432, 12288,
        196608, 12288, 12582912, 4096, 12288, 4194304, 4194304, 4194304,
        4194304, 4096, 4096, 2097152, 2048, 2097152, 2048, 2097152, 2048,
        2097152, 2048, 9216, 3 };
    int bad = (n_in == 29) ? -1 : 29;
    if (bad < 0)
        for (int i = 0; i < 29; ++i)
            if (in_sizes[i] != expected[i]) { bad = i; break; }
    if (bad >= 0) {
        diag_k<<<24, 256, 0, stream>>>(out, 1000.f + 8.f * bad);
        return;
    }

    // ---- workspace layout (56.8 MB total) ----------------------------------
    const size_t REQ = 64 + 3ull * 8388608 + 8388608 + 16777216 + 8388608 + 786432;
    if (ws_size < REQ) {
        diag_k<<<24, 256, 0, stream>>>(out, 2048.f + (float)(ws_size >> 20));
        return;
    }
    char* base = (char*)d_ws;
    int*   flag = (int*)base;
    float* resM = (float*)(base + 64);
    float* resR = resM + 2097152;
    float* resT = resR + 2097152;
    float* bufN = resT + 2097152;                 // fp32 xn (NBL*D) / bf16 delta (NBL*DI)
    bf16*  XZ16 = (bf16*)(bufN + 2097152);        // NBL*4096
    bf16*  U16  = XZ16 + (size_t)NBL * 4096;      // NBL*2048
    float* XD   = (float*)(U16 + (size_t)NBL * 2048); // NBL*96

    // quarter views of XZ16 (NBL*1024 each, contiguous)
    bf16* q0 = XZ16;
    bf16* q1 = XZ16 + 1 * 2097152;
    bf16* q2 = XZ16 + 2 * 2097152;
    bf16* q3 = XZ16 + 3 * 2097152;
    bf16* u0 = U16;
    bf16* u1 = U16 + 2097152;

    const void* x        = d_in[0];
    const void* m_norm   = d_in[1];
    const void* m_Win    = d_in[2];
    const void* m_conv_w = d_in[3];
    const void* m_conv_b = d_in[4];
    const void* m_Wx     = d_in[5];
    const void* m_Wdt    = d_in[6];
    const void* m_bdt    = d_in[7];
    const void* m_Alog   = d_in[8];
    const void* m_D      = d_in[9];
    const void* m_Wout   = d_in[10];
    const void* r_norm   = d_in[11];
    const void* r_mu     = d_in[12];
    const void* r_Wr     = d_in[13];
    const void* r_Wk     = d_in[14];
    const void* r_Wv     = d_in[15];
    const void* r_Wo     = d_in[16];
    const void* r_wlog   = d_in[17];
    const void* r_u      = d_in[18];
    const void* a_Wq     = d_in[19];
    const void* a_bq     = d_in[20];
    const void* a_Wk     = d_in[21];
    const void* a_bk     = d_in[22];
    const void* a_Wv     = d_in[23];
    const void* a_bv     = d_in[24];
    const void* a_Wo     = d_in[25];
    const void* a_bo     = d_in[26];
    const void* f_W      = d_in[27];
    const void* f_b      = d_in[28];

    auto gemm = [&](const void* A, int lda, int aDt, const void* W, long woff,
                    const void* bias, long boff, int hasBias,
                    void* C, int ldc, int cDt, int N, int K, int act, int acc) {
        dim3 g((N + BN - 1) / BN, NBL / BM);
        gemm_k<<<g, 256, 0, stream>>>(A, lda, aDt, W, woff, bias, boff, hasBias,
                                      C, ldc, cDt, N, K, act, acc, flag);
    };

    detect_k<<<1, 64, 0, stream>>>(x, flag);
    cast3_k<<<8192, 256, 0, stream>>>(x, resM, resR, resT, flag);

    // ---------------- Mamba branch ----------------
    for (int i = 0; i < NM_; ++i) {
        rmsnorm_k<<<NBL, 256, 0, stream>>>(resM, m_norm, (long)i * D_, bufN, flag);
        gemm(bufN, D_, 0, m_Win, (long)i * D_ * 2 * DI_, nullptr, 0, 0,
             XZ16, 2 * DI_, 1, 2 * DI_, D_, 0, 0);
        conv_silu_k<<<16384, 256, 0, stream>>>(XZ16, m_conv_w, (long)i * KC_ * DI_,
                                               m_conv_b, (long)i * DI_, U16, flag);
        gemm(U16, DI_, 1, m_Wx, (long)i * DI_ * 96, nullptr, 0, 0,
             XD, 96, 0, 96, DI_, 0, 0);
        gemm(XD, 96, 0, m_Wdt, (long)i * DTR_ * DI_, m_bdt, (long)i * DI_, 1,
             bufN, DI_, 1, DI_, DTR_, 1 /*softplus*/, 0);
        mamba_scan_k<<<B_ * DI_, 256, 0, stream>>>(U16, (const bf16*)bufN, XD, XZ16,
            m_Alog, (long)i * DI_ * DS_, m_D, (long)i * DI_, flag);
        gemm(XZ16, 2 * DI_, 1, m_Wout, (long)i * DI_ * D_, nullptr, 0, 0,
             resM, D_, 0, D_, DI_, 0, 1 /*acc*/);
    }

    // ---------------- RWKV branch ----------------
    for (int i = 0; i < NR_; ++i) {
        rmsnorm_k<<<NBL, 256, 0, stream>>>(resR, r_norm, (long)i * D_, bufN, flag);
        rwkv_mix_k<<<8192, 256, 0, stream>>>(bufN, r_mu, (long)i * 3 * D_,
                                             q0, q1, q2, flag);
        gemm(q0, D_, 1, r_Wr, (long)i * D_ * D_, nullptr, 0, 0, u0, D_, 1, D_, D_, 0, 0);
        gemm(q1, D_, 1, r_Wk, (long)i * D_ * D_, nullptr, 0, 0, u1, D_, 1, D_, D_, 0, 0);
        gemm(q2, D_, 1, r_Wv, (long)i * D_ * D_, nullptr, 0, 0, q3, D_, 1, D_, D_, 0, 0);
        rwkv_scan_k<<<B_ * HR_ * DHR_, RW_NCH * 64, 0, stream>>>(u0, u1, q3,
            r_wlog, (long)i * HR_ * DHR_, r_u, (long)i * HR_ * DHR_, q0, flag);
        gemm(q0, D_, 1, r_Wo, (long)i * D_ * D_, nullptr, 0, 0, resR, D_, 0, D_, D_, 0, 1);
    }

    // ---------------- MHA branch (no norm, no residual) ----------------
    for (int i = 0; i < NT_; ++i) {
        gemm(resT, D_, 0, a_Wq, (long)i * D_ * HA_ * DHA_, a_bq, (long)i * HA_ * DHA_, 1,
             u0, D_, 1, D_, D_, 0, 0);
        gemm(resT, D_, 0, a_Wk, (long)i * D_ * HA_ * DHA_, a_bk, (long)i * HA_ * DHA_, 1,
             u1, D_, 1, D_, D_, 0, 0);
        gemm(resT, D_, 0, a_Wv, (long)i * D_ * HA_ * DHA_, a_bv, (long)i * HA_ * DHA_, 1,
             q3, D_, 1, D_, D_, 0, 0);
        mha_attn_k<<<dim3(L_ / 64, HA_, B_), 256, 0, stream>>>(u0, u1, q3, q0);
        gemm(q0, D_, 1, a_Wo, (long)i * HA_ * DHA_ * D_, a_bo, (long)i * D_, 1,
             resT, D_, 0, D_, HA_ * DHA_, 0, 0 /*no residual*/);
    }

    // ---------------- combine + softmax ----------------
    final_k<<<NBL, 256, 0, stream>>>(resM, resR, resT, f_W, f_b, out, flag);
}

// Round 5
// 4030.125 us; speedup vs baseline: 3.3335x; 1.0343x over previous
//
#include <hip/hip_runtime.h>
#include <hip/hip_bf16.h>
#include <cstddef>

#define D_   1024
#define DI_  2048
#define DS_  16
#define DTR_ 64
#define KC_  4
#define HR_  16
#define DHR_ 64
#define HA_  32
#define DHA_ 32
#define NM_  6
#define NR_  4
#define NT_  2
#define B_   2
#define L_   1024
#define NBL  (B_*L_)   // 2048 rows

typedef __hip_bfloat16 bf16;
typedef __attribute__((ext_vector_type(8))) short short8v;   // 8 bf16 (4 VGPRs)
typedef __attribute__((ext_vector_type(4))) float float4v;   // MFMA C/D frag

__device__ __forceinline__ float bfbits2f(unsigned short u) {
    return __uint_as_float(((unsigned int)u) << 16);
}
__device__ __forceinline__ float b2f(bf16 x) { return __bfloat162float(x); }
__device__ __forceinline__ unsigned short f2bfbits(float f) {
    bf16 h = __float2bfloat16(f);
    return *reinterpret_cast<unsigned short*>(&h);
}
// dtype-dispatched model-input load: bf==1 -> bf16, bf==0 -> fp32
__device__ __forceinline__ float ldf(const void* p, long i, int bf) {
    if (bf) return bfbits2f(((const unsigned short*)p)[i]);
    return ((const float*)p)[i];
}
__device__ __forceinline__ float softplus_f(float x) {
    return x > 20.f ? x : log1pf(__expf(x));
}
__device__ __forceinline__ float silu_f(float x) {
    return x / (1.f + __expf(-x));
}

// ---------------------------------------------------------------------------
// Diagnostic writer (fp32 out): zeros the output, writes a code into out[0].
// ---------------------------------------------------------------------------
__global__ __launch_bounds__(256) void diag_k(float* __restrict__ out, float code)
{
    const int idx = blockIdx.x * 256 + threadIdx.x;
    if (idx < NBL * 3) out[idx] = (idx == 0 ? code : 0.f);
}

// ---------------------------------------------------------------------------
// Input dtype detection (1 wave).
// ---------------------------------------------------------------------------
__global__ __launch_bounds__(64) void detect_k(const void* __restrict__ x,
                                               int* __restrict__ flag)
{
    const unsigned short* u = (const unsigned short*)x;
    int local = 0;
    for (int i = threadIdx.x; i < 1024; i += 64) {
        const float av = fabsf(bfbits2f(u[i]));
        if (!(av < 1e6f)) local = 1;   // catches huge and NaN
    }
    const unsigned long long b = __ballot(local);
    if (threadIdx.x == 0) flag[0] = b ? 0 : 1;  // 1 => inputs are bf16
}

// ---------------------------------------------------------------------------
// MFMA GEMM: C[M,N] = act(A[M,K] @ W[K,N] + bias) (+ C if acc, fp32 C only)
// Tile 64x64, TK=64. 4 waves, each a 32x32 sub-tile (2x2 fragments).
// ---------------------------------------------------------------------------
#define BM 64
#define BN 64
#define TK 64
#define LDT 72

__global__ __launch_bounds__(256) void gemm_k(
    const void* __restrict__ A, int lda, int aDt,
    const void* __restrict__ W, long woff,
    const void* __restrict__ bias, long boff, int hasBias,
    void* __restrict__ C, int ldc, int cDt,
    int N, int K, int act, int acc,
    const int* __restrict__ flagp)
{
    const int bf = *flagp;
    __shared__ short As[BM * LDT];
    __shared__ short Bs[BN * LDT];
    const int bm = blockIdx.y * BM;
    const int bn = blockIdx.x * BN;
    const int tid = threadIdx.x;
    const int lane = tid & 63;
    const int wid = tid >> 6;
    const int wr = wid >> 1, wc = wid & 1;

    // staging indices
    const int sa_row = tid >> 2;            // 0..63
    const int sa_kq  = (tid & 3) << 4;      // 0,16,32,48
    const int sb_col = tid & 63;            // 0..63 (wave-coalesced in n)
    const int sb_kq  = (tid >> 6) << 4;     // 0,16,32,48
    const int sb_gn  = bn + sb_col;

    float4v accv[2][2] = {};

    for (int k0 = 0; k0 < K; k0 += TK) {
        // ---- stage A tile (64 rows x 64 k) ----
        {
            short8v a0, a1;
            const size_t aoff = (size_t)(bm + sa_row) * lda + k0 + sa_kq;
            if (aDt) {
                a0 = *(const short8v*)((const unsigned short*)A + aoff);
                a1 = *(const short8v*)((const unsigned short*)A + aoff + 8);
            } else {
                const float* ap = (const float*)A + aoff;
                const float4 v0 = *(const float4*)(ap + 0);
                const float4 v1 = *(const float4*)(ap + 4);
                const float4 v2 = *(const float4*)(ap + 8);
                const float4 v3 = *(const float4*)(ap + 12);
                a0[0]=f2bfbits(v0.x); a0[1]=f2bfbits(v0.y); a0[2]=f2bfbits(v0.z); a0[3]=f2bfbits(v0.w);
                a0[4]=f2bfbits(v1.x); a0[5]=f2bfbits(v1.y); a0[6]=f2bfbits(v1.z); a0[7]=f2bfbits(v1.w);
                a1[0]=f2bfbits(v2.x); a1[1]=f2bfbits(v2.y); a1[2]=f2bfbits(v2.z); a1[3]=f2bfbits(v2.w);
                a1[4]=f2bfbits(v3.x); a1[5]=f2bfbits(v3.y); a1[6]=f2bfbits(v3.z); a1[7]=f2bfbits(v3.w);
            }
            *(short8v*)&As[sa_row * LDT + sa_kq + 0] = a0;
            *(short8v*)&As[sa_row * LDT + sa_kq + 8] = a1;
        }
        // ---- stage B tile transposed: Bs[col][k] (64 cols x 64 k) ----
        {
            short8v b0, b1;
            #pragma unroll
            for (int j = 0; j < 8; ++j) { b0[j] = 0; b1[j] = 0; }
            if (sb_gn < N) {
                const long wbase = woff + (long)(k0 + sb_kq) * N + sb_gn;
                if (bf) {
                    const unsigned short* wp = (const unsigned short*)W;
                    #pragma unroll
                    for (int j = 0; j < 8; ++j) {
                        b0[j] = (short)wp[wbase + (long)j * N];
                        b1[j] = (short)wp[wbase + (long)(j + 8) * N];
                    }
                } else {
                    const float* wp = (const float*)W;
                    #pragma unroll
                    for (int j = 0; j < 8; ++j) {
                        b0[j] = (short)f2bfbits(wp[wbase + (long)j * N]);
                        b1[j] = (short)f2bfbits(wp[wbase + (long)(j + 8) * N]);
                    }
                }
            }
            *(short8v*)&Bs[sb_col * LDT + sb_kq + 0] = b0;
            *(short8v*)&Bs[sb_col * LDT + sb_kq + 8] = b1;
        }
        __syncthreads();
        // ---- MFMA: 8 per wave per K-tile ----
        {
            const int r  = lane & 15;
            const int kb = (lane >> 4) << 3;   // 0,8,16,24
            #pragma unroll
            for (int ks = 0; ks < TK; ks += 32) {
                const int kg = ks + kb;
                const short8v a0 = *(const short8v*)&As[(wr*32 +      r) * LDT + kg];
                const short8v a1 = *(const short8v*)&As[(wr*32 + 16 + r) * LDT + kg];
                const short8v b0 = *(const short8v*)&Bs[(wc*32 +      r) * LDT + kg];
                const short8v b1 = *(const short8v*)&Bs[(wc*32 + 16 + r) * LDT + kg];
                accv[0][0] = __builtin_amdgcn_mfma_f32_16x16x32_bf16(a0, b0, accv[0][0], 0, 0, 0);
                accv[0][1] = __builtin_amdgcn_mfma_f32_16x16x32_bf16(a0, b1, accv[0][1], 0, 0, 0);
                accv[1][0] = __builtin_amdgcn_mfma_f32_16x16x32_bf16(a1, b0, accv[1][0], 0, 0, 0);
                accv[1][1] = __builtin_amdgcn_mfma_f32_16x16x32_bf16(a1, b1, accv[1][1], 0, 0, 0);
            }
        }
        __syncthreads();
    }

    // ---- epilogue: C/D layout col=lane&15, row=(lane>>4)*4+j (m89) ----
    const int crow0 = bm + wr * 32 + ((lane >> 4) << 2);
    const int ccol0 = bn + wc * 32 + (lane & 15);
    #pragma unroll
    for (int ni = 0; ni < 2; ++ni) {
        const int col = ccol0 + ni * 16;
        if (col < N) {
            const float bsv = hasBias ? ldf(bias, boff + col, bf) : 0.f;
            #pragma unroll
            for (int mi = 0; mi < 2; ++mi) {
                #pragma unroll
                for (int j = 0; j < 4; ++j) {
                    const int row = crow0 + mi * 16 + j;
                    float r = accv[mi][ni][j] + bsv;
                    if (act == 1) r = softplus_f(r);
                    if (cDt) {
                        ((bf16*)C)[(size_t)row * ldc + col] = __float2bfloat16(r);
                    } else {
                        float* cp = (float*)C + (size_t)row * ldc + col;
                        if (acc) r += *cp;
                        *cp = r;
                    }
                }
            }
        }
    }
}

// ---------------------------------------------------------------------------
__global__ __launch_bounds__(256) void cast3_k(const void* __restrict__ x,
    float* __restrict__ a, float* __restrict__ b, float* __restrict__ c,
    const int* __restrict__ flagp)
{
    const int bf = *flagp;
    const int idx = blockIdx.x * 256 + threadIdx.x;
    const float v = ldf(x, idx, bf);
    a[idx] = v; b[idx] = v; c[idx] = v;
}

// ---------------------------------------------------------------------------
__global__ __launch_bounds__(256) void rmsnorm_k(const float* __restrict__ x,
    const void* __restrict__ wgt, long woff, float* __restrict__ out,
    const int* __restrict__ flagp)
{
    const int bf = *flagp;
    const int row = blockIdx.x;
    const float* xr = x + (size_t)row * D_;
    float ss = 0.f;
    for (int i = threadIdx.x; i < D_; i += 256) { const float v = xr[i]; ss = fmaf(v, v, ss); }
    #pragma unroll
    for (int msk = 1; msk < 64; msk <<= 1) ss += __shfl_xor(ss, msk);
    __shared__ float red[4];
    if ((threadIdx.x & 63) == 0) red[threadIdx.x >> 6] = ss;
    __syncthreads();
    ss = red[0] + red[1] + red[2] + red[3];
    const float scale = rsqrtf(ss * (1.f / D_) + 1e-6f);
    float* orow = out + (size_t)row * D_;
    for (int i = threadIdx.x; i < D_; i += 256)
        orow[i] = xr[i] * scale * ldf(wgt, woff + i, bf);
}

// ---------------------------------------------------------------------------
// Depthwise causal conv (K=4) + SiLU. xc = cols [0,DI) of xz16 (stride 2*DI).
// ---------------------------------------------------------------------------
__global__ __launch_bounds__(256) void conv_silu_k(const bf16* __restrict__ xz,
    const void* __restrict__ cw, long cwoff, const void* __restrict__ cb, long cboff,
    bf16* __restrict__ out, const int* __restrict__ flagp)
{
    const int bf = *flagp;
    const int idx = blockIdx.x * 256 + threadIdx.x;
    const int c = idx & (DI_ - 1);
    const int l = (idx >> 11) & (L_ - 1);
    const int b = idx >> 21;
    float acc = ldf(cb, cboff + c, bf);
    #pragma unroll
    for (int j = 0; j < KC_; ++j) {
        const int ls = l - (KC_ - 1) + j;
        if (ls >= 0)
            acc = fmaf(b2f(xz[((size_t)(b * L_ + ls)) * (2 * DI_) + c]),
                       ldf(cw, cwoff + j * DI_ + c, bf), acc);
    }
    out[idx] = __float2bfloat16(silu_f(acc));
}

// ---------------------------------------------------------------------------
// Mamba selective scan — chunk-parallel (linear recurrence is associative).
// XCD-swizzled blockIdx: one block per (b,d); its 2-byte strided loads/stores
// use 1/64th of each 128B line, and the 64 d-neighbor blocks that share the
// line must land on the SAME XCD L2 to avoid 8x fetch/write amplification.
// hw%8 == XCD (m09), so orig = (hw&7)*512 + hw>>3 gives each XCD a
// contiguous 512-block d-range (4096%8==0 => bijective, ERRATA #11 ok).
// ---------------------------------------------------------------------------
#define MS_NCH 16
#define MS_CH  (L_ / MS_NCH)   // 64

__global__ __launch_bounds__(256) void mamba_scan_k(
    const bf16* __restrict__ u, const bf16* __restrict__ dlt,
    const float* __restrict__ xdbl, bf16* __restrict__ xz,
    const void* __restrict__ Alog, long aoff, const void* __restrict__ Dp, long doff,
    const int* __restrict__ flagp)
{
    const int bf = *flagp;
    const int bid = ((blockIdx.x & 7) << 9) | (blockIdx.x >> 3);  // XCD swizzle, B*DI = 4096
    const int d = bid & (DI_ - 1);
    const int b = bid >> 11;
    const int s = threadIdx.x & (DS_ - 1);
    const int c = threadIdx.x >> 4;        // chunk 0..15
    const float Av = -__expf(ldf(Alog, aoff + d * DS_ + s, bf));
    const float Dv = ldf(Dp, doff + d, bf);

    __shared__ float Pl[MS_NCH][DS_];
    __shared__ float Sl[MS_NCH][DS_];

    const int l0 = c * MS_CH;

    // pass 1: chunk-local (P, S)
    float P = 1.f, S = 0.f;
    for (int i = 0; i < MS_CH; ++i) {
        const size_t row = (size_t)(b * L_ + l0 + i);
        const float ut = b2f(u[row * DI_ + d]);
        const float dt = b2f(dlt[row * DI_ + d]);
        const float Bv = xdbl[row * 96 + 64 + s];
        const float dA = __expf(dt * Av);
        P *= dA;
        S = fmaf(S, dA, dt * ut * Bv);
    }
    Pl[c][s] = P; Sl[c][s] = S;
    __syncthreads();

    // prefix combine: h at this chunk's start
    float hs = 0.f;
    for (int cc = 0; cc < c; ++cc) hs = fmaf(hs, Pl[cc][s], Sl[cc][s]);

    // pass 2: rescan with true h0, reduce over s, write y
    for (int i = 0; i < MS_CH; ++i) {
        const size_t row = (size_t)(b * L_ + l0 + i);
        const float ut = b2f(u[row * DI_ + d]);
        const float dt = b2f(dlt[row * DI_ + d]);
        const float Bv = xdbl[row * 96 + 64 + s];
        const float Cv = xdbl[row * 96 + 80 + s];
        const float dA = __expf(dt * Av);
        hs = fmaf(hs, dA, dt * ut * Bv);
        float yp = hs * Cv;
        yp += __shfl_xor(yp, 1, 16);
        yp += __shfl_xor(yp, 2, 16);
        yp += __shfl_xor(yp, 4, 16);
        yp += __shfl_xor(yp, 8, 16);
        if (s == 0) {
            const float z = b2f(xz[row * (2 * DI_) + DI_ + d]);
            xz[row * (2 * DI_) + d] = __float2bfloat16((yp + Dv * ut) * silu_f(z));
        }
    }
}

// ---------------------------------------------------------------------------
__global__ __launch_bounds__(256) void rwkv_mix_k(const float* __restrict__ xn,
    const void* __restrict__ mu, long muoff, bf16* __restrict__ o0,
    bf16* __restrict__ o1, bf16* __restrict__ o2, const int* __restrict__ flagp)
{
    const int bf = *flagp;
    const int idx = blockIdx.x * 256 + threadIdx.x;
    const int d = idx & (D_ - 1);
    const int l = (idx >> 10) & (L_ - 1);
    const float cur = xn[idx];
    const float prev = (l > 0) ? xn[idx - D_] : 0.f;
    const float m0 = ldf(mu, muoff + d, bf);
    const float m1 = ldf(mu, muoff + D_ + d, bf);
    const float m2 = ldf(mu, muoff + 2 * D_ + d, bf);
    o0[idx] = __float2bfloat16(cur * m0 + prev * (1.f - m0));
    o1[idx] = __float2bfloat16(cur * m1 + prev * (1.f - m1));
    o2[idx] = __float2bfloat16(cur * m2 + prev * (1.f - m2));
}

// ---------------------------------------------------------------------------
// RWKV scan — chunk-parallel (constant w => chunk carry in closed form).
// XCD-swizzled blockIdx (2048 blocks, 2048%8==0): consecutive-v blocks write
// adjacent 2B of the same line; keeping them on one XCD merges writes in L2.
// ---------------------------------------------------------------------------
#define RW_NCH 16
#define RW_CH  (L_ / RW_NCH)   // 64

__global__ __launch_bounds__(1024) void rwkv_scan_k(const bf16* __restrict__ R,
    const bf16* __restrict__ Kb, const bf16* __restrict__ V,
    const void* __restrict__ wlog, long woff, const void* __restrict__ uu, long uoff,
    bf16* __restrict__ Y, const int* __restrict__ flagp)
{
    const int bf = *flagp;
    const int bid = ((blockIdx.x & 7) << 8) | (blockIdx.x >> 3);  // XCD swizzle, B*HR*DHR = 2048
    const int v = bid & (DHR_ - 1);
    const int h = (bid >> 6) & (HR_ - 1);
    const int b = bid >> 10;
    const int k = threadIdx.x & 63;
    const int c = threadIdx.x >> 6;       // chunk 0..15
    const float ew = __expf(ldf(wlog, woff + h * DHR_ + k, bf));
    const float w  = __expf(-ew);
    const float wC = __expf(-ew * (float)RW_CH);   // w^CH
    const float uv = ldf(uu, uoff + h * DHR_ + k, bf);

    __shared__ float Se[RW_NCH][64];

    const int l0 = c * RW_CH;

    // pass 1: chunk-local S_end (S0 = 0)
    float S = 0.f;
    for (int i = 0; i < RW_CH; ++i) {
        const size_t off = ((size_t)(b * L_ + l0 + i)) * D_ + h * DHR_;
        const float kk = b2f(Kb[off + k]);
        const float vt = b2f(V[off + v]);
        S = fmaf(w, S, kk * vt);
    }
    Se[c][k] = S;
    __syncthreads();

    // prefix: S at this chunk's start
    S = 0.f;
    for (int cc = 0; cc < c; ++cc) S = fmaf(wC, S, Se[cc][k]);

    // pass 2: rescan with true S0, reduce over k, write y
    for (int i = 0; i < RW_CH; ++i) {
        const size_t off = ((size_t)(b * L_ + l0 + i)) * D_ + h * DHR_;
        const float r  = b2f(R[off + k]);
        const float kk = b2f(Kb[off + k]);
        const float vt = b2f(V[off + v]);
        const float kv = kk * vt;
        float yp = r * fmaf(uv, kv, S);
        S = fmaf(w, S, kv);
        yp += __shfl_xor(yp, 1);
        yp += __shfl_xor(yp, 2);
        yp += __shfl_xor(yp, 4);
        yp += __shfl_xor(yp, 8);
        yp += __shfl_xor(yp, 16);
        yp += __shfl_xor(yp, 32);
        if (k == 0) Y[off + v] = __float2bfloat16(yp);
    }
}

// ---------------------------------------------------------------------------
// MHA flash attention — MFMA version (see round 4 notes).
// ---------------------------------------------------------------------------
#define LDK 40   // Ks row pitch (bf16): 80B, 16B-aligned, 2-way banks (free)
#define LDV 72   // Vt/Ps row pitch (bf16): 144B, 16B-aligned, 2-way banks

__global__ __launch_bounds__(256) void mha_attn_k(const bf16* __restrict__ Q,
    const bf16* __restrict__ Kx, const bf16* __restrict__ V, bf16* __restrict__ O)
{
    const int b = blockIdx.z, h = blockIdx.y;
    const int qt = blockIdx.x;            // 0..15
    const int tid = threadIdx.x;
    const int lane = tid & 63;
    const int wid = tid >> 6;

    __shared__ __align__(16) short Ks[64 * LDK];
    __shared__ __align__(16) short Vt[32 * LDV];
    __shared__ __align__(16) short Ps[4][16 * LDV];

    const int fc  = lane & 15;            // A-row / B-col within fragment
    const int g   = lane >> 4;            // k-octet group; C rows = g*4+j
    const int fk8 = g << 3;               // 0,8,16,24

    const int q0 = qt * 64 + wid * 16;

    // Q fragment (K=32 = full head dim), loaded once
    const size_t qoff = ((size_t)(b * L_ + q0 + fc)) * D_ + h * DHA_ + fk8;
    const short8v qf = *(const short8v*)((const unsigned short*)Q + qoff);

    float4v o0 = {}, o1 = {};
    float m[4] = {-1e30f, -1e30f, -1e30f, -1e30f};
    float l[4] = {0.f, 0.f, 0.f, 0.f};
    const float scale = 0.1767766952966369f;   // 1/sqrt(32)

    // staging indices: thread t covers (row=t>>2, d-octet=(t&3)*8)
    const int sr = tid >> 2;
    const int sc = (tid & 3) << 3;

    for (int kt = 0; kt < L_; kt += 64) {
        __syncthreads();   // all waves done reading previous Ks/Vt
        {
            const size_t koff = ((size_t)(b * L_ + kt + sr)) * D_ + h * DHA_ + sc;
            const short8v k8 = *(const short8v*)((const unsigned short*)Kx + koff);
            *(short8v*)&Ks[sr * LDK + sc] = k8;
            const short8v v8 = *(const short8v*)((const unsigned short*)V + koff);
            #pragma unroll
            for (int j = 0; j < 8; ++j)
                Vt[(sc + j) * LDV + sr] = v8[j];
        }
        __syncthreads();

        // ---- QK^T: 4 mfma over 4 kv-16 sub-tiles ----
        float4v sv[4];
        #pragma unroll
        for (int nt = 0; nt < 4; ++nt) {
            const short8v kf = *(const short8v*)&Ks[(nt * 16 + fc) * LDK + fk8];
            float4v z = {};
            sv[nt] = __builtin_amdgcn_mfma_f32_16x16x32_bf16(qf, kf, z, 0, 0, 0);
        }

        // ---- online softmax (rows g*4+j, cols nt*16+fc) ----
        #pragma unroll
        for (int j = 0; j < 4; ++j) {
            float mt = fmaxf(fmaxf(sv[0][j], sv[1][j]), fmaxf(sv[2][j], sv[3][j])) * scale;
            #pragma unroll
            for (int msk = 1; msk < 16; msk <<= 1) mt = fmaxf(mt, __shfl_xor(mt, msk));
            const float mn = fmaxf(m[j], mt);
            const float corr = __expf(m[j] - mn);
            m[j] = mn;
            float sum = 0.f;
            #pragma unroll
            for (int nt = 0; nt < 4; ++nt) {
                const float p = __expf(fmaf(sv[nt][j], scale, -mn));
                sum += p;
                Ps[wid][(g * 4 + j) * LDV + nt * 16 + fc] = (short)f2bfbits(p);
            }
            #pragma unroll
            for (int msk = 1; msk < 16; msk <<= 1) sum += __shfl_xor(sum, msk);
            l[j] = l[j] * corr + sum;
            o0[j] *= corr;
            o1[j] *= corr;
        }

        // ---- PV: O += P(16x64) . V(64x32), 2 k-chunks x 2 d-tiles ----
        #pragma unroll
        for (int kc = 0; kc < 2; ++kc) {
            const short8v pf = *(const short8v*)&Ps[wid][fc * LDV + kc * 32 + fk8];
            const short8v v0 = *(const short8v*)&Vt[(fc) * LDV + kc * 32 + fk8];
            const short8v v1 = *(const short8v*)&Vt[(16 + fc) * LDV + kc * 32 + fk8];
            o0 = __builtin_amdgcn_mfma_f32_16x16x32_bf16(pf, v0, o0, 0, 0, 0);
            o1 = __builtin_amdgcn_mfma_f32_16x16x32_bf16(pf, v1, o1, 0, 0, 0);
        }
    }

    // ---- epilogue ----
    #pragma unroll
    for (int j = 0; j < 4; ++j) {
        const float inv = 1.f / l[j];
        const size_t ooff = ((size_t)(b * L_ + q0 + g * 4 + j)) * D_ + h * DHA_;
        O[ooff + fc]      = __float2bfloat16(o0[j] * inv);
        O[ooff + 16 + fc] = __float2bfloat16(o1[j] * inv);
    }
}

// ---------------------------------------------------------------------------
// Final: logits = [m,r,t] @ f_W + f_b; softmax over 3; fp32 out.
// ---------------------------------------------------------------------------
__global__ __launch_bounds__(256) void final_k(const float* __restrict__ m,
    const float* __restrict__ r, const float* __restrict__ t,
    const void* __restrict__ fW, const void* __restrict__ fb,
    float* __restrict__ out, const int* __restrict__ flagp)
{
    const int bf = *flagp;
    const int row = blockIdx.x;
    float p0 = 0.f, p1 = 0.f, p2 = 0.f;
    for (int i = threadIdx.x; i < 3 * D_; i += 256) {
        float v;
        if (i < D_)          v = m[(size_t)row * D_ + i];
        else if (i < 2 * D_) v = r[(size_t)row * D_ + i - D_];
        else                 v = t[(size_t)row * D_ + i - 2 * D_];
        p0 = fmaf(v, ldf(fW, (long)i * 3 + 0, bf), p0);
        p1 = fmaf(v, ldf(fW, (long)i * 3 + 1, bf), p1);
        p2 = fmaf(v, ldf(fW, (long)i * 3 + 2, bf), p2);
    }
    #pragma unroll
    for (int msk = 1; msk < 64; msk <<= 1) {
        p0 += __shfl_xor(p0, msk);
        p1 += __shfl_xor(p1, msk);
        p2 += __shfl_xor(p2, msk);
    }
    __shared__ float red[4][3];
    if ((threadIdx.x & 63) == 0) {
        const int w = threadIdx.x >> 6;
        red[w][0] = p0; red[w][1] = p1; red[w][2] = p2;
    }
    __syncthreads();
    if (threadIdx.x == 0) {
        const float l0 = red[0][0] + red[1][0] + red[2][0] + red[3][0] + ldf(fb, 0, bf);
        const float l1 = red[0][1] + red[1][1] + red[2][1] + red[3][1] + ldf(fb, 1, bf);
        const float l2 = red[0][2] + red[1][2] + red[2][2] + red[3][2] + ldf(fb, 2, bf);
        const float mx = fmaxf(l0, fmaxf(l1, l2));
        const float e0 = __expf(l0 - mx), e1 = __expf(l1 - mx), e2 = __expf(l2 - mx);
        const float inv = 1.f / (e0 + e1 + e2);
        out[row * 3 + 0] = e0 * inv;
        out[row * 3 + 1] = e1 * inv;
        out[row * 3 + 2] = e2 * inv;
    }
}

// ---------------------------------------------------------------------------
extern "C" void kernel_launch(void* const* d_in, const int* in_sizes, int n_in,
                              void* d_out, int out_size, void* d_ws, size_t ws_size,
                              hipStream_t stream)
{
    float* out = (float*)d_out;

    // ---- self-diagnosis: verify input sizes (dict order) -------------------
    static const int expected[29] = {
        2097152, 6144, 25165824, 49152, 12288, 1179648, 786432, 12288,
        196608, 12288, 12582912, 4096, 12288, 4194304, 4194304, 4194304,
        4194304, 4096, 4096, 2097152, 2048, 2097152, 2048, 2097152, 2048,
        2097152, 2048, 9216, 3 };
    int bad = (n_in == 29) ? -1 : 29;
    if (bad < 0)
        for (int i = 0; i < 29; ++i)
            if (in_sizes[i] != expected[i]) { bad = i; break; }
    if (bad >= 0) {
        diag_k<<<24, 256, 0, stream>>>(out, 1000.f + 8.f * bad);
        return;
    }

    // ---- workspace layout (56.8 MB total) ----------------------------------
    const size_t REQ = 64 + 3ull * 8388608 + 8388608 + 16777216 + 8388608 + 786432;
    if (ws_size < REQ) {
        diag_k<<<24, 256, 0, stream>>>(out, 2048.f + (float)(ws_size >> 20));
        return;
    }
    char* base = (char*)d_ws;
    int*   flag = (int*)base;
    float* resM = (float*)(base + 64);
    float* resR = resM + 2097152;
    float* resT = resR + 2097152;
    float* bufN = resT + 2097152;                 // fp32 xn (NBL*D) / bf16 delta (NBL*DI)
    bf16*  XZ16 = (bf16*)(bufN + 2097152);        // NBL*4096
    bf16*  U16  = XZ16 + (size_t)NBL * 4096;      // NBL*2048
    float* XD   = (float*)(U16 + (size_t)NBL * 2048); // NBL*96

    // quarter views of XZ16 (NBL*1024 each, contiguous)
    bf16* q0 = XZ16;
    bf16* q1 = XZ16 + 1 * 2097152;
    bf16* q2 = XZ16 + 2 * 2097152;
    bf16* q3 = XZ16 + 3 * 2097152;
    bf16* u0 = U16;
    bf16* u1 = U16 + 2097152;

    const void* x        = d_in[0];
    const void* m_norm   = d_in[1];
    const void* m_Win    = d_in[2];
    const void* m_conv_w = d_in[3];
    const void* m_conv_b = d_in[4];
    const void* m_Wx     = d_in[5];
    const void* m_Wdt    = d_in[6];
    const void* m_bdt    = d_in[7];
    const void* m_Alog   = d_in[8];
    const void* m_D      = d_in[9];
    const void* m_Wout   = d_in[10];
    const void* r_norm   = d_in[11];
    const void* r_mu     = d_in[12];
    const void* r_Wr     = d_in[13];
    const void* r_Wk     = d_in[14];
    const void* r_Wv     = d_in[15];
    const void* r_Wo     = d_in[16];
    const void* r_wlog   = d_in[17];
    const void* r_u      = d_in[18];
    const void* a_Wq     = d_in[19];
    const void* a_bq     = d_in[20];
    const void* a_Wk     = d_in[21];
    const void* a_bk     = d_in[22];
    const void* a_Wv     = d_in[23];
    const void* a_bv     = d_in[24];
    const void* a_Wo     = d_in[25];
    const void* a_bo     = d_in[26];
    const void* f_W      = d_in[27];
    const void* f_b      = d_in[28];

    auto gemm = [&](const void* A, int lda, int aDt, const void* W, long woff,
                    const void* bias, long boff, int hasBias,
                    void* C, int ldc, int cDt, int N, int K, int act, int acc) {
        dim3 g((N + BN - 1) / BN, NBL / BM);
        gemm_k<<<g, 256, 0, stream>>>(A, lda, aDt, W, woff, bias, boff, hasBias,
                                      C, ldc, cDt, N, K, act, acc, flag);
    };

    detect_k<<<1, 64, 0, stream>>>(x, flag);
    cast3_k<<<8192, 256, 0, stream>>>(x, resM, resR, resT, flag);

    // ---------------- Mamba branch ----------------
    for (int i = 0; i < NM_; ++i) {
        rmsnorm_k<<<NBL, 256, 0, stream>>>(resM, m_norm, (long)i * D_, bufN, flag);
        gemm(bufN, D_, 0, m_Win, (long)i * D_ * 2 * DI_, nullptr, 0, 0,
             XZ16, 2 * DI_, 1, 2 * DI_, D_, 0, 0);
        conv_silu_k<<<16384, 256, 0, stream>>>(XZ16, m_conv_w, (long)i * KC_ * DI_,
                                               m_conv_b, (long)i * DI_, U16, flag);
        gemm(U16, DI_, 1, m_Wx, (long)i * DI_ * 96, nullptr, 0, 0,
             XD, 96, 0, 96, DI_, 0, 0);
        gemm(XD, 96, 0, m_Wdt, (long)i * DTR_ * DI_, m_bdt, (long)i * DI_, 1,
             bufN, DI_, 1, DI_, DTR_, 1 /*softplus*/, 0);
        mamba_scan_k<<<B_ * DI_, 256, 0, stream>>>(U16, (const bf16*)bufN, XD, XZ16,
            m_Alog, (long)i * DI_ * DS_, m_D, (long)i * DI_, flag);
        gemm(XZ16, 2 * DI_, 1, m_Wout, (long)i * DI_ * D_, nullptr, 0, 0,
             resM, D_, 0, D_, DI_, 0, 1 /*acc*/);
    }

    // ---------------- RWKV branch ----------------
    for (int i = 0; i < NR_; ++i) {
        rmsnorm_k<<<NBL, 256, 0, stream>>>(resR, r_norm, (long)i * D_, bufN, flag);
        rwkv_mix_k<<<8192, 256, 0, stream>>>(bufN, r_mu, (long)i * 3 * D_,
                                             q0, q1, q2, flag);
        gemm(q0, D_, 1, r_Wr, (long)i * D_ * D_, nullptr, 0, 0, u0, D_, 1, D_, D_, 0, 0);
        gemm(q1, D_, 1, r_Wk, (long)i * D_ * D_, nullptr, 0, 0, u1, D_, 1, D_, D_, 0, 0);
        gemm(q2, D_, 1, r_Wv, (long)i * D_ * D_, nullptr, 0, 0, q3, D_, 1, D_, D_, 0, 0);
        rwkv_scan_k<<<B_ * HR_ * DHR_, RW_NCH * 64, 0, stream>>>(u0, u1, q3,
            r_wlog, (long)i * HR_ * DHR_, r_u, (long)i * HR_ * DHR_, q0, flag);
        gemm(q0, D_, 1, r_Wo, (long)i * D_ * D_, nullptr, 0, 0, resR, D_, 0, D_, D_, 0, 1);
    }

    // ---------------- MHA branch (no norm, no residual) ----------------
    for (int i = 0; i < NT_; ++i) {
        gemm(resT, D_, 0, a_Wq, (long)i * D_ * HA_ * DHA_, a_bq, (long)i * HA_ * DHA_, 1,
             u0, D_, 1, D_, D_, 0, 0);
        gemm(resT, D_, 0, a_Wk, (long)i * D_ * HA_ * DHA_, a_bk, (long)i * HA_ * DHA_, 1,
             u1, D_, 1, D_, D_, 0, 0);
        gemm(resT, D_, 0, a_Wv, (long)i * D_ * HA_ * DHA_, a_bv, (long)i * HA_ * DHA_, 1,
             q3, D_, 1, D_, D_, 0, 0);
        mha_attn_k<<<dim3(L_ / 64, HA_, B_), 256, 0, stream>>>(u0, u1, q3, q0);
        gemm(q0, D_, 1, a_Wo, (long)i * HA_ * DHA_ * D_, a_bo, (long)i * D_, 1,
             resT, D_, 0, D_, HA_ * DHA_, 0, 0 /*no residual*/);
    }

    // ---------------- combine + softmax ----------------
    final_k<<<NBL, 256, 0, stream>>>(resM, resR, resT, f_W, f_b, out, flag);
}